// Round 3
// baseline (500.280 us; speedup 1.0000x reference)
//
#include <hip/hip_runtime.h>

typedef unsigned short u16;
typedef __bf16 bf16x8 __attribute__((ext_vector_type(8)));
typedef float f32x4 __attribute__((ext_vector_type(4)));
typedef int i32x4 __attribute__((ext_vector_type(4)));
// may_alias: LDS/global buffers are accessed as u16, i32x4 and bf16x8 — without
// this, TBAA lets the compiler reorder the P-matrix u16 stores vs bf16x8 loads.
typedef i32x4 i32x4_a __attribute__((may_alias));
typedef bf16x8 bf16x8_a __attribute__((may_alias));

__device__ __forceinline__ float bf2f(u16 u) {
  union { unsigned int i; float f; } c;
  c.i = ((unsigned int)u) << 16;
  return c.f;
}
// Native cast -> v_cvt_pk_bf16_f32 (RNE) instead of 4-5 op software RNE.
__device__ __forceinline__ u16 f2bf(float f) {
  union { __bf16 h; u16 u; } c;
  c.h = (__bf16)f;
  return c.u;
}
// dual-dtype scalar load: isbf ? bf16[i] : f32[i]
__device__ __forceinline__ float gld(const void* p, int i, int isbf) {
  return isbf ? bf2f(((const u16*)p)[i]) : ((const float*)p)[i];
}
// XOR-swizzled LDS element offset (16B blocks swizzled by row low 3 bits).
__device__ __forceinline__ int sw(int row, int col, int rs) {
  return row * rs + ((((col >> 3) ^ (row & 7)) << 3) | (col & 7));
}

// ws layout (bytes):
//   0      : wqkvT  bf16 [384][128]   (98304)
//   98304  : pwT    bf16 [128][128]   (32768)
//   131072 : qkvb   f32  [384]        (1536)
//   132608 : bias16 f32  [4][64][64]  (65536)  == 16*sigmoid(cpb MLP)[h][q][k]
//   198144 : scalef f32  [4]          (16)     == exp(min(logit_scale, ln100))
//   198160 : pbf    f32  [128]        (512)
//   198672 : flag   u32  (1=bf16 inputs, 0=f32 inputs)
#define WQKVT_OFF 0
#define PWT_OFF   98304
#define QKVB_OFF  131072
#define BIAS_OFF  132608
#define SCALE_OFF 198144
#define PB_OFF    198160
#define FLAG_OFF  198672

// ---------------- dtype probe ----------------
__global__ void swin_detect(const unsigned int* __restrict__ xw,
                            unsigned int* __restrict__ flag) {
  int t = threadIdx.x;  // 64 threads
  int cnt = 0;
  for (int i = 0; i < 8; i++) {
    unsigned int w = xw[t * 8 + i];
    unsigned int lo = w & 0xffffu;
    unsigned int e = (lo >> 7) & 0xffu;
    if ((e >= 0x70u && e <= 0x82u) || lo == 0u) cnt++;
  }
  cnt += __shfl_xor(cnt, 1);
  cnt += __shfl_xor(cnt, 2);
  cnt += __shfl_xor(cnt, 4);
  cnt += __shfl_xor(cnt, 8);
  cnt += __shfl_xor(cnt, 16);
  cnt += __shfl_xor(cnt, 32);
  if (t == 0) *flag = (cnt >= 256) ? 1u : 0u;
}

// ---------------- setup v2 ----------------
__global__ void swin_setup(const void* __restrict__ qkv_w, const void* __restrict__ q_bias,
                           const void* __restrict__ v_bias, const void* __restrict__ ls,
                           const void* __restrict__ cpb_w1, const void* __restrict__ cpb_b1,
                           const void* __restrict__ cpb_w2, const void* __restrict__ proj_w,
                           const void* __restrict__ proj_b, char* __restrict__ ws) {
  const int b = blockIdx.x, t = threadIdx.x;
  const int isbf = (int)*(const unsigned int*)(ws + FLAG_OFF);
  u16* wqkvT = (u16*)(ws + WQKVT_OFF);
  u16* pwT = (u16*)(ws + PWT_OFF);
  float* qkvb = (float*)(ws + QKVB_OFF);
  float* bias16 = (float*)(ws + BIAS_OFF);
  float* scalef = (float*)(ws + SCALE_OFF);
  float* pbf = (float*)(ws + PB_OFF);

  if (b < 128) {           // qkv_w row b: coalesced read, scattered write
    for (int c = t; c < 384; c += 256)
      wqkvT[c * 128 + b] = f2bf(gld(qkv_w, b * 384 + c, isbf));
  } else if (b < 256) {    // proj_w row (b-128)
    int r = b - 128;
    if (t < 128) pwT[t * 128 + r] = f2bf(gld(proj_w, r * 128 + t, isbf));
  } else if (b == 256) {   // small vectors
    for (int o = t; o < 384; o += 256) {
      float v = 0.f;
      if (o < 128) v = gld(q_bias, o, isbf);
      else if (o >= 256) v = gld(v_bias, o - 256, isbf);
      qkvb[o] = v;
    }
    if (t < 128) pbf[t] = gld(proj_b, t, isbf);
    if (t < 4) scalef[t] = expf(fminf(gld(ls, t, isbf), 4.60517019f));
  } else {                 // CPB MLP -> 16*sigmoid, gathered by rel-pos index
    __shared__ float w1[1024];   // [2][512]
    __shared__ float b1[512];
    __shared__ float w2[2048];   // [512][4]
    __shared__ float tab[225][4];
    for (int i = t; i < 1024; i += 256) w1[i] = gld(cpb_w1, i, isbf);
    for (int i = t; i < 512; i += 256) b1[i] = gld(cpb_b1, i, isbf);
    for (int i = t; i < 2048; i += 256) w2[i] = gld(cpb_w2, i, isbf);
    __syncthreads();
    if (t < 225) {
      int i = t / 15, j = t % 15;
      float c0, c1;
      {
        float tt = ((float)(i - 7) / 7.0f) * 8.0f;
        float s = (tt > 0.f) ? 1.f : ((tt < 0.f) ? -1.f : 0.f);
        c0 = s * log2f(fabsf(tt) + 1.f) / 3.0f;
      }
      {
        float tt = ((float)(j - 7) / 7.0f) * 8.0f;
        float s = (tt > 0.f) ? 1.f : ((tt < 0.f) ? -1.f : 0.f);
        c1 = s * log2f(fabsf(tt) + 1.f) / 3.0f;
      }
      float acc[4] = {0.f, 0.f, 0.f, 0.f};
      for (int jj = 0; jj < 512; jj++) {
        float h = fmaxf(c0 * w1[jj] + c1 * w1[512 + jj] + b1[jj], 0.f);
        #pragma unroll
        for (int hh = 0; hh < 4; hh++) acc[hh] += h * w2[jj * 4 + hh];
      }
      #pragma unroll
      for (int hh = 0; hh < 4; hh++) tab[t][hh] = acc[hh];
    }
    __syncthreads();
    for (int e = t; e < 4 * 64 * 64; e += 256) {
      int h = e >> 12, q = (e >> 6) & 63, kk = e & 63;
      int dr = (q >> 3) - (kk >> 3) + 7;
      int dc = (q & 7) - (kk & 7) + 7;
      float v = tab[dr * 15 + dc][h];
      bias16[e] = 16.f / (1.f + expf(-v));
    }
  }
}

// ---------------- fused per-window kernel (round-5) ----------------
// One block per window (B*256 blocks), 512 threads = 8 waves.
// Round-5 post-mortem of round-4 (250us == round-2's 248.6):
//   LDS shrink to 48KB landed (LDS_Block_Size=49152) but OccupancyPercent
//   stayed 45%: __launch_bounds__(512,4) gives a 128-reg/wave budget, and at
//   128 regs the REGISTER FILE caps residency at 4 waves/SIMD = 16 waves/CU =
//   50% — same ceiling LDS used to impose. Round-3 measured 63% occupancy at
//   (512,6) but spilled (~700MB scratch traffic) because GEMM1's live peak
//   (48 acc + 24 B-frag + 8 A-frag + addr ~= 100 regs) >> the 80-reg budget.
// Fix: GEMM1 split into 3 passes of one 32-col chunk (acc[2][2]=16 regs, B
//   frags 8), epilogue per chunk so accs die immediately. K/V chunk results
//   write LDS at once (regions disjoint from X); Q chunk results are HELD in
//   registers as packed bf16 pairs (<=24 regs, q-owning waves only) and
//   written after the barrier into the then-dead X region. asm memory clobber
//   between chunks stops CSE of the X fragment loads (which would rebuild the
//   register peak). Barrier count unchanged (7). Peak live ~70 regs -> fits
//   the (512,6) budget, no spill -> 3 blocks/CU.
// Success criterion vs round-3's failure: WRITE_SIZE stays 131072 KB
//   (no scratch); occupancy ~63%.
// LDS (u16 elements, 24576 total = 48KB), lifetime-aliased:
//   stage1-2: X [0,8192)   K [8192,16384) VT [16384,24576)  (K/VT filled during GEMM1)
//   stage2-3: Q [0,8192)   K [8192,16384) VT [16384,24576)
//   stage4-5: P [0,16384)  VT [16384,24576)
//   stage5-6: AO [0,8192)
#define X_OFF 0
#define Q_OFF 0
#define K_OFF 8192
#define VT_OFF 16384
#define P_OFF 0
#define AO_OFF 0

__global__ __launch_bounds__(512, 6) void swin_main(
    const void* __restrict__ x, const void* __restrict__ mask,
    const char* __restrict__ ws, void* __restrict__ out) {
  __shared__ __align__(16) u16 lds[24576];
  const f32x4 fz = {0.f, 0.f, 0.f, 0.f};

  const u16* wqkvT = (const u16*)(ws + WQKVT_OFF);
  const u16* pwT = (const u16*)(ws + PWT_OFF);
  const float* qkvb = (const float*)(ws + QKVB_OFF);
  const float* bias16 = (const float*)(ws + BIAS_OFF);
  const float* scalef = (const float*)(ws + SCALE_OFF);
  const float* pbf = (const float*)(ws + PB_OFF);
  const int isbf = (int)*(const unsigned int*)(ws + FLAG_OFF);

  const int tid = threadIdx.x;
  const int wid = tid >> 6;
  const int lane = tid & 63;
  const int ln16 = lane & 15;
  const int lq = lane >> 4;
  const int q8 = lq << 3;
  const int mg = wid >> 2;   // row half: 0/1
  const int sub = wid & 3;   // col slice / head

  const int wi = blockIdx.x;
  const int b = wi >> 8;
  const int rem = wi & 255;
  const int wy = rem >> 4, wx = rem & 15;
  const int xbase = ((b * 128 + wy * 8) * 128 + wx * 8) * 128;

  // ---- stage 1: X tile -> LDS as bf16 (coalesced) ----
  if (isbf) {
    const u16* xb = (const u16*)x;
    #pragma unroll
    for (int rep = 0; rep < 2; rep++) {
      int ch = tid + rep * 512;          // 1024 chunks of 8 elements
      int token = ch >> 4, dch = ch & 15;
      int r = token >> 3, c = token & 7;
      i32x4 v = *(const i32x4_a*)(xb + xbase + r * 16384 + c * 128 + dch * 8);
      *(i32x4_a*)(lds + X_OFF + sw(token, dch * 8, 128)) = v;
    }
  } else {
    const float* xf = (const float*)x;
    #pragma unroll
    for (int rep = 0; rep < 2; rep++) {
      int ch = tid + rep * 512;
      int token = ch >> 4, dch = ch & 15;
      int r = token >> 3, c = token & 7;
      const float* src = xf + xbase + r * 16384 + c * 128 + dch * 8;
      union { i32x4 v2[2]; float f[8]; } in;
      in.v2[0] = *(const i32x4_a*)(src);
      in.v2[1] = *(const i32x4_a*)(src + 4);
      union { u16 u[8]; i32x4 v; } o;
      #pragma unroll
      for (int d = 0; d < 8; d++) o.u[d] = f2bf(in.f[d]);
      *(i32x4_a*)(lds + X_OFF + sw(token, dch * 8, 128)) = o.v;
    }
  }
  __syncthreads();

  // ---- stage 2: GEMM1  qkv = X @ Wqkv + b, one 32-col chunk per pass ----
  // hq[ci]: packed (lo16=col ln16, hi16=col 16+ln16) bf16 results for q-chunks,
  // written to LDS only after the barrier (Q region overlays live X).
  unsigned int hq[3][8];
  #pragma unroll
  for (int ci = 0; ci < 3; ci++) {
    const int n0 = 96 * sub + 32 * ci;
    const int type = n0 >> 7;              // 0=q 1=k 2=v
    const int head = (n0 & 127) >> 5;
    f32x4 acc[2][2];
    #pragma unroll
    for (int nt = 0; nt < 2; nt++) {
      float bv = qkvb[n0 + 16 * nt + ln16];
      f32x4 ci4 = {bv, bv, bv, bv};
      acc[0][nt] = ci4;
      acc[1][nt] = ci4;
    }
    #pragma unroll
    for (int ks = 0; ks < 4; ks++) {
      bf16x8 a0 = *(const bf16x8_a*)(lds + X_OFF + sw(32 * mg + ln16, 32 * ks + q8, 128));
      bf16x8 a1 = *(const bf16x8_a*)(lds + X_OFF + sw(32 * mg + 16 + ln16, 32 * ks + q8, 128));
      bf16x8 b0 = *(const bf16x8_a*)(wqkvT + (n0 + ln16) * 128 + 32 * ks + q8);
      bf16x8 b1 = *(const bf16x8_a*)(wqkvT + (n0 + 16 + ln16) * 128 + 32 * ks + q8);
      acc[0][0] = __builtin_amdgcn_mfma_f32_16x16x32_bf16(a0, b0, acc[0][0], 0, 0, 0);
      acc[0][1] = __builtin_amdgcn_mfma_f32_16x16x32_bf16(a0, b1, acc[0][1], 0, 0, 0);
      acc[1][0] = __builtin_amdgcn_mfma_f32_16x16x32_bf16(a1, b0, acc[1][0], 0, 0, 0);
      acc[1][1] = __builtin_amdgcn_mfma_f32_16x16x32_bf16(a1, b1, acc[1][1], 0, 0, 0);
    }
    // per-chunk epilogue: acc dies here
    if (type < 2) {
      float sh = (type == 0) ? scalef[head] : 1.0f;  // fold logit scale into q
      #pragma unroll
      for (int mt = 0; mt < 2; mt++)
        #pragma unroll
        for (int r = 0; r < 4; r++) {
          float x0 = acc[mt][0][r], x1 = acc[mt][1][r];
          float ss = x0 * x0 + x1 * x1;
          ss += __shfl_xor(ss, 1);
          ss += __shfl_xor(ss, 2);
          ss += __shfl_xor(ss, 4);
          ss += __shfl_xor(ss, 8);
          float inv = sh / fmaxf(sqrtf(ss), 1e-12f);
          u16 lo = f2bf(x0 * inv), hi = f2bf(x1 * inv);
          if (type == 0) {
            hq[ci][mt * 4 + r] = (unsigned int)lo | ((unsigned int)hi << 16);
          } else {
            int row = 32 * mg + 16 * mt + 4 * lq + r;
            lds[K_OFF + sw(row, head * 32 + ln16, 128)] = lo;
            lds[K_OFF + sw(row, head * 32 + 16 + ln16, 128)] = hi;
          }
        }
    } else {
      #pragma unroll
      for (int mt = 0; mt < 2; mt++)
        #pragma unroll
        for (int r = 0; r < 4; r++) {
          int row = 32 * mg + 16 * mt + 4 * lq + r;
          lds[VT_OFF + sw(head * 32 + ln16, row, 64)] = f2bf(acc[mt][0][r]);
          lds[VT_OFF + sw(head * 32 + 16 + ln16, row, 64)] = f2bf(acc[mt][1][r]);
        }
    }
    // stop CSE of the X fragment loads across chunks (would rebuild reg peak)
    asm volatile("" ::: "memory");
  }
  __syncthreads();  // all waves done reading X; K/VT writes visible

  // write held q chunks into Q region (overlays dead X)
  #pragma unroll
  for (int ci = 0; ci < 3; ci++) {
    const int n0 = 96 * sub + 32 * ci;
    if ((n0 >> 7) == 0) {
      const int head = (n0 & 127) >> 5;
      #pragma unroll
      for (int mt = 0; mt < 2; mt++)
        #pragma unroll
        for (int r = 0; r < 4; r++) {
          unsigned int pv = hq[ci][mt * 4 + r];
          int row = 32 * mg + 16 * mt + 4 * lq + r;
          lds[Q_OFF + sw(row, head * 32 + ln16, 128)] = (u16)(pv & 0xffffu);
          lds[Q_OFF + sw(row, head * 32 + 16 + ln16, 128)] = (u16)(pv >> 16);
        }
    }
  }
  __syncthreads();

  // ---- stage 3: S = (q*scale).k^T + bias + mask (as MFMA C), softmax ----
  const int h = sub;
  bf16x8 qf[2], kf[4];
  #pragma unroll
  for (int mt = 0; mt < 2; mt++)
    qf[mt] = *(const bf16x8_a*)(lds + Q_OFF + sw(32 * mg + 16 * mt + ln16, h * 32 + q8, 128));
  #pragma unroll
  for (int nt = 0; nt < 4; nt++)
    kf[nt] = *(const bf16x8_a*)(lds + K_OFF + sw(16 * nt + ln16, h * 32 + q8, 128));

  // preload bias+mask as the MFMA C operand: loads issue before the MFMAs
  const float* brow = bias16 + h * 4096;
  const u16* mk16 = (const u16*)mask;
  const float* mkf = (const float*)mask;
  f32x4 S[2][4];
  #pragma unroll
  for (int mt = 0; mt < 2; mt++)
    #pragma unroll
    for (int nt = 0; nt < 4; nt++)
      #pragma unroll
      for (int r = 0; r < 4; r++) {
        int row = 32 * mg + 16 * mt + 4 * lq + r;
        int col = 16 * nt + ln16;
        int bi = row * 64 + col;
        float mval = isbf ? bf2f(mk16[rem * 4096 + bi]) : mkf[rem * 4096 + bi];
        S[mt][nt][r] = brow[bi] + mval;
      }
  #pragma unroll
  for (int mt = 0; mt < 2; mt++)
    #pragma unroll
    for (int nt = 0; nt < 4; nt++)
      S[mt][nt] = __builtin_amdgcn_mfma_f32_16x16x32_bf16(qf[mt], kf[nt], S[mt][nt], 0, 0, 0);

  #pragma unroll
  for (int mt = 0; mt < 2; mt++)
    #pragma unroll
    for (int r = 0; r < 4; r++) {
      float m = fmaxf(fmaxf(S[mt][0][r], S[mt][1][r]), fmaxf(S[mt][2][r], S[mt][3][r]));
      m = fmaxf(m, __shfl_xor(m, 1));
      m = fmaxf(m, __shfl_xor(m, 2));
      m = fmaxf(m, __shfl_xor(m, 4));
      m = fmaxf(m, __shfl_xor(m, 8));
      float sum = 0.f;
      #pragma unroll
      for (int nt = 0; nt < 4; nt++) {
        float p = __expf(S[mt][nt][r] - m);
        S[mt][nt][r] = p;
        sum += p;
      }
      sum += __shfl_xor(sum, 1);
      sum += __shfl_xor(sum, 2);
      sum += __shfl_xor(sum, 4);
      sum += __shfl_xor(sum, 8);
      float inv = 1.0f / sum;
      #pragma unroll
      for (int nt = 0; nt < 4; nt++) S[mt][nt][r] *= inv;
    }
  __syncthreads();  // everyone done reading Q/K before P overlays them

  // ---- stage 4/5: P -> LDS, O = P @ V ----
  #pragma unroll
  for (int mt = 0; mt < 2; mt++)
    #pragma unroll
    for (int nt = 0; nt < 4; nt++)
      #pragma unroll
      for (int r = 0; r < 4; r++) {
        int row = 32 * mg + 16 * mt + 4 * lq + r;
        lds[P_OFF + sw(row, h * 64 + 16 * nt + ln16, 256)] = f2bf(S[mt][nt][r]);
      }
  __syncthreads();  // order P stores before P vector loads (and cross-wave safety)
  f32x4 O[2][2];
  O[0][0] = fz; O[0][1] = fz; O[1][0] = fz; O[1][1] = fz;
  #pragma unroll
  for (int ks = 0; ks < 2; ks++) {
    bf16x8 pf[2], vf[2];
    #pragma unroll
    for (int mt = 0; mt < 2; mt++)
      pf[mt] = *(const bf16x8_a*)(lds + P_OFF + sw(32 * mg + 16 * mt + ln16, h * 64 + 32 * ks + q8, 256));
    #pragma unroll
    for (int nt = 0; nt < 2; nt++)
      vf[nt] = *(const bf16x8_a*)(lds + VT_OFF + sw(h * 32 + 16 * nt + ln16, 32 * ks + q8, 64));
    #pragma unroll
    for (int mt = 0; mt < 2; mt++)
      #pragma unroll
      for (int nt = 0; nt < 2; nt++)
        O[mt][nt] = __builtin_amdgcn_mfma_f32_16x16x32_bf16(pf[mt], vf[nt], O[mt][nt], 0, 0, 0);
  }
  __syncthreads();  // all waves done reading P before AO overlays it
  #pragma unroll
  for (int mt = 0; mt < 2; mt++)
    #pragma unroll
    for (int nt = 0; nt < 2; nt++)
      #pragma unroll
      for (int r = 0; r < 4; r++) {
        int row = 32 * mg + 16 * mt + 4 * lq + r;
        lds[AO_OFF + sw(row, h * 32 + 16 * nt + ln16, 128)] = f2bf(O[mt][nt][r]);
      }
  __syncthreads();

  // ---- stage 6: out = AO @ proj_w + proj_b (bias folded into C init) ----
  float pb0 = pbf[32 * sub + ln16];
  float pb1 = pbf[32 * sub + 16 + ln16];
  f32x4 acc3[2][2];
  {
    f32x4 c0 = {pb0, pb0, pb0, pb0};
    f32x4 c1 = {pb1, pb1, pb1, pb1};
    acc3[0][0] = c0; acc3[0][1] = c1; acc3[1][0] = c0; acc3[1][1] = c1;
  }
  #pragma unroll
  for (int ks = 0; ks < 4; ks++) {
    bf16x8 a0 = *(const bf16x8_a*)(lds + AO_OFF + sw(32 * mg + ln16, 32 * ks + q8, 128));
    bf16x8 a1 = *(const bf16x8_a*)(lds + AO_OFF + sw(32 * mg + 16 + ln16, 32 * ks + q8, 128));
    bf16x8 b0 = *(const bf16x8_a*)(pwT + (32 * sub + ln16) * 128 + 32 * ks + q8);
    bf16x8 b1 = *(const bf16x8_a*)(pwT + (32 * sub + 16 + ln16) * 128 + 32 * ks + q8);
    acc3[0][0] = __builtin_amdgcn_mfma_f32_16x16x32_bf16(a0, b0, acc3[0][0], 0, 0, 0);
    acc3[0][1] = __builtin_amdgcn_mfma_f32_16x16x32_bf16(a0, b1, acc3[0][1], 0, 0, 0);
    acc3[1][0] = __builtin_amdgcn_mfma_f32_16x16x32_bf16(a1, b0, acc3[1][0], 0, 0, 0);
    acc3[1][1] = __builtin_amdgcn_mfma_f32_16x16x32_bf16(a1, b1, acc3[1][1], 0, 0, 0);
  }
  if (isbf) {
    u16* ob = (u16*)out;
    #pragma unroll
    for (int mt = 0; mt < 2; mt++)
      #pragma unroll
      for (int r = 0; r < 4; r++) {
        int row = 32 * mg + 16 * mt + 4 * lq + r;
        int o = xbase + (row >> 3) * 16384 + (row & 7) * 128 + 32 * sub;
        ob[o + ln16] = f2bf(acc3[mt][0][r]);
        ob[o + 16 + ln16] = f2bf(acc3[mt][1][r]);
      }
  } else {
    float* of = (float*)out;
    #pragma unroll
    for (int mt = 0; mt < 2; mt++)
      #pragma unroll
      for (int r = 0; r < 4; r++) {
        int row = 32 * mg + 16 * mt + 4 * lq + r;
        int o = xbase + (row >> 3) * 16384 + (row & 7) * 128 + 32 * sub;
        of[o + ln16] = acc3[mt][0][r];
        of[o + 16 + ln16] = acc3[mt][1][r];
      }
  }
}

extern "C" void kernel_launch(void* const* d_in, const int* in_sizes, int n_in,
                              void* d_out, int out_size, void* d_ws, size_t ws_size,
                              hipStream_t stream) {
  const void* x      = d_in[0];
  const void* mask   = d_in[1];
  const void* qkv_w  = d_in[2];
  const void* q_bias = d_in[3];
  const void* v_bias = d_in[4];
  const void* ls     = d_in[5];
  const void* cpb_w1 = d_in[6];
  const void* cpb_b1 = d_in[7];
  const void* cpb_w2 = d_in[8];
  const void* proj_w = d_in[9];
  const void* proj_b = d_in[10];
  const int B = in_sizes[0] / (128 * 128 * 128);

  char* ws = (char*)d_ws;
  swin_detect<<<1, 64, 0, stream>>>((const unsigned int*)x,
                                    (unsigned int*)(ws + FLAG_OFF));
  swin_setup<<<258, 256, 0, stream>>>(qkv_w, q_bias, v_bias, ls, cpb_w1, cpb_b1,
                                      cpb_w2, proj_w, proj_b, ws);
  swin_main<<<B * 256, 512, 0, stream>>>(x, mask, ws, d_out);
}

// Round 4
// 494.773 us; speedup vs baseline: 1.0111x; 1.0111x over previous
//
#include <hip/hip_runtime.h>

typedef unsigned short u16;
typedef __bf16 bf16x8 __attribute__((ext_vector_type(8)));
typedef float f32x4 __attribute__((ext_vector_type(4)));
typedef int i32x4 __attribute__((ext_vector_type(4)));
typedef int i32x2 __attribute__((ext_vector_type(2)));
// may_alias: LDS/global buffers are accessed as u16, i32x2/4, f32x4 and bf16x8 —
// without this, TBAA lets the compiler reorder the P-matrix stores vs loads.
typedef i32x4 i32x4_a __attribute__((may_alias));
typedef i32x2 i32x2_a __attribute__((may_alias));
typedef bf16x8 bf16x8_a __attribute__((may_alias));
typedef f32x4 f32x4_a __attribute__((may_alias));
typedef unsigned long long u64_a __attribute__((may_alias));

__device__ __forceinline__ float bf2f(u16 u) {
  union { unsigned int i; float f; } c;
  c.i = ((unsigned int)u) << 16;
  return c.f;
}
// Native cast -> v_cvt_pk_bf16_f32 (RNE) instead of 4-5 op software RNE.
__device__ __forceinline__ u16 f2bf(float f) {
  union { __bf16 h; u16 u; } c;
  c.h = (__bf16)f;
  return c.u;
}
// dual-dtype scalar load: isbf ? bf16[i] : f32[i]
__device__ __forceinline__ float gld(const void* p, int i, int isbf) {
  return isbf ? bf2f(((const u16*)p)[i]) : ((const float*)p)[i];
}
// XOR-swizzled LDS element offset (16B blocks swizzled by row low 3 bits).
__device__ __forceinline__ int sw(int row, int col, int rs) {
  return row * rs + ((((col >> 3) ^ (row & 7)) << 3) | (col & 7));
}
// A-fragment of X loaded straight from global (row-major window layout:
// token row (r,c) lives at (r>>3)*16384 + (r&7)*128; rows 0-7 are a contiguous
// 2KB span, L1/L2-served, re-read 4x per block by the mg-sharing waves).
__device__ __forceinline__ bf16x8 ldx(const void* x, int base, int row, int d, int isbf) {
  int off = base + ((row >> 3) * 16384) + ((row & 7) * 128) + d;
  if (isbf) {
    return *(const bf16x8_a*)((const u16*)x + off);
  } else {
    const float* p = (const float*)x + off;
    union { u16 u[8]; bf16x8 v; } o;
    #pragma unroll
    for (int i = 0; i < 8; i++) o.u[i] = f2bf(p[i]);
    return o.v;
  }
}

// ws layout (bytes):
//   0      : wqkvT  bf16 [384][128]   (98304)
//   98304  : pwT    bf16 [128][128]   (32768)
//   131072 : qkvb   f32  [384]        (1536)
//   132608 : bias16 f32  [4][64][64]  (65536)  == 16*sigmoid(cpb MLP)[h][q][k]
//   198144 : scalef f32  [4]          (16)     == exp(min(logit_scale, ln100))
//   198160 : pbf    f32  [128]        (512)
//   198672 : flag   u32  (1=bf16 inputs, 0=f32 inputs)
#define WQKVT_OFF 0
#define PWT_OFF   98304
#define QKVB_OFF  131072
#define BIAS_OFF  132608
#define SCALE_OFF 198144
#define PB_OFF    198160
#define FLAG_OFF  198672

// ---------------- dtype probe ----------------
__global__ void swin_detect(const unsigned int* __restrict__ xw,
                            unsigned int* __restrict__ flag) {
  int t = threadIdx.x;  // 64 threads
  int cnt = 0;
  for (int i = 0; i < 8; i++) {
    unsigned int w = xw[t * 8 + i];
    unsigned int lo = w & 0xffffu;
    unsigned int e = (lo >> 7) & 0xffu;
    if ((e >= 0x70u && e <= 0x82u) || lo == 0u) cnt++;
  }
  cnt += __shfl_xor(cnt, 1);
  cnt += __shfl_xor(cnt, 2);
  cnt += __shfl_xor(cnt, 4);
  cnt += __shfl_xor(cnt, 8);
  cnt += __shfl_xor(cnt, 16);
  cnt += __shfl_xor(cnt, 32);
  if (t == 0) *flag = (cnt >= 256) ? 1u : 0u;
}

// ---------------- setup v2 ----------------
__global__ void swin_setup(const void* __restrict__ qkv_w, const void* __restrict__ q_bias,
                           const void* __restrict__ v_bias, const void* __restrict__ ls,
                           const void* __restrict__ cpb_w1, const void* __restrict__ cpb_b1,
                           const void* __restrict__ cpb_w2, const void* __restrict__ proj_w,
                           const void* __restrict__ proj_b, char* __restrict__ ws) {
  const int b = blockIdx.x, t = threadIdx.x;
  const int isbf = (int)*(const unsigned int*)(ws + FLAG_OFF);
  u16* wqkvT = (u16*)(ws + WQKVT_OFF);
  u16* pwT = (u16*)(ws + PWT_OFF);
  float* qkvb = (float*)(ws + QKVB_OFF);
  float* bias16 = (float*)(ws + BIAS_OFF);
  float* scalef = (float*)(ws + SCALE_OFF);
  float* pbf = (float*)(ws + PB_OFF);

  if (b < 128) {           // qkv_w row b: coalesced read, scattered write
    for (int c = t; c < 384; c += 256)
      wqkvT[c * 128 + b] = f2bf(gld(qkv_w, b * 384 + c, isbf));
  } else if (b < 256) {    // proj_w row (b-128)
    int r = b - 128;
    if (t < 128) pwT[t * 128 + r] = f2bf(gld(proj_w, r * 128 + t, isbf));
  } else if (b == 256) {   // small vectors
    for (int o = t; o < 384; o += 256) {
      float v = 0.f;
      if (o < 128) v = gld(q_bias, o, isbf);
      else if (o >= 256) v = gld(v_bias, o - 256, isbf);
      qkvb[o] = v;
    }
    if (t < 128) pbf[t] = gld(proj_b, t, isbf);
    if (t < 4) scalef[t] = expf(fminf(gld(ls, t, isbf), 4.60517019f));
  } else {                 // CPB MLP -> 16*sigmoid, gathered by rel-pos index
    __shared__ float w1[1024];   // [2][512]
    __shared__ float b1[512];
    __shared__ float w2[2048];   // [512][4]
    __shared__ float tab[225][4];
    for (int i = t; i < 1024; i += 256) w1[i] = gld(cpb_w1, i, isbf);
    for (int i = t; i < 512; i += 256) b1[i] = gld(cpb_b1, i, isbf);
    for (int i = t; i < 2048; i += 256) w2[i] = gld(cpb_w2, i, isbf);
    __syncthreads();
    if (t < 225) {
      int i = t / 15, j = t % 15;
      float c0, c1;
      {
        float tt = ((float)(i - 7) / 7.0f) * 8.0f;
        float s = (tt > 0.f) ? 1.f : ((tt < 0.f) ? -1.f : 0.f);
        c0 = s * log2f(fabsf(tt) + 1.f) / 3.0f;
      }
      {
        float tt = ((float)(j - 7) / 7.0f) * 8.0f;
        float s = (tt > 0.f) ? 1.f : ((tt < 0.f) ? -1.f : 0.f);
        c1 = s * log2f(fabsf(tt) + 1.f) / 3.0f;
      }
      float acc[4] = {0.f, 0.f, 0.f, 0.f};
      for (int jj = 0; jj < 512; jj++) {
        float h = fmaxf(c0 * w1[jj] + c1 * w1[512 + jj] + b1[jj], 0.f);
        #pragma unroll
        for (int hh = 0; hh < 4; hh++) acc[hh] += h * w2[jj * 4 + hh];
      }
      #pragma unroll
      for (int hh = 0; hh < 4; hh++) tab[t][hh] = acc[hh];
    }
    __syncthreads();
    for (int e = t; e < 4 * 64 * 64; e += 256) {
      int h = e >> 12, q = (e >> 6) & 63, kk = e & 63;
      int dr = (q >> 3) - (kk >> 3) + 7;
      int dc = (q & 7) - (kk & 7) + 7;
      float v = tab[dr * 15 + dc][h];
      bias16[e] = 16.f / (1.f + expf(-v));
    }
  }
}

// ---------------- fused per-window kernel (round-6 rework) ----------------
// One block per window (B*256 blocks), 512 threads = 8 waves.
// Round-6 post-mortem of round-5 (317us, spilled AGAIN at (512,6)):
//   85-reg total budget is unreachable for this structure (two attempts, both
//   40 arch VGPR + massive scratch). Occupancy is pinned at 2 blocks/CU; the
//   249us baseline is ~80% STALL (issue-cycle estimate ~100k of 600k cycles):
//   7 barriers/block + 64-shuffle softmax chains + 96-shuffle norm chains
//   dominate. Round-4 proved VALU-count cuts alone don't move time ->
//   attack serialization at fixed occupancy:
//   1. X LDS staging dropped: GEMM1 A-fragments load straight from global
//      (L1/L2-served, rows 2KB-contiguous). Removes stage-1 + 2 barriers.
//   2. Swapped QK^T: S^T = mfma(kf, qf). Softmax k-reduction = in-reg fmax
//      + xor16/xor32 (8 shuffles vs 64); bias+mask C-init becomes f32x4/8B
//      vector loads (k is the register axis now); P stores = 8x 8B (vs 32
//      scalar). P LDS content bit-identical to round-4 -> PV/proj untouched.
//   3. Barriers 7 -> 5.
// Success criteria: WRITE_SIZE stays 131072 KB (no spill), dur ~190-205us.
// LDS (u16 elements, 24576 total = 48KB), lifetime-aliased:
//   stage2-3: Q [0,8192) K [8192,16384) VT [16384,24576)
//   stage4-5: P [0,16384) VT [16384,24576)
//   stage5-6: AO [0,8192)
#define Q_OFF 0
#define K_OFF 8192
#define VT_OFF 16384
#define P_OFF 0
#define AO_OFF 0

__global__ __launch_bounds__(512, 4) void swin_main(
    const void* __restrict__ x, const void* __restrict__ mask,
    const char* __restrict__ ws, void* __restrict__ out) {
  __shared__ __align__(16) u16 lds[24576];
  const f32x4 fz = {0.f, 0.f, 0.f, 0.f};

  const u16* wqkvT = (const u16*)(ws + WQKVT_OFF);
  const u16* pwT = (const u16*)(ws + PWT_OFF);
  const float* qkvb = (const float*)(ws + QKVB_OFF);
  const float* bias16 = (const float*)(ws + BIAS_OFF);
  const float* scalef = (const float*)(ws + SCALE_OFF);
  const float* pbf = (const float*)(ws + PB_OFF);
  const int isbf = (int)*(const unsigned int*)(ws + FLAG_OFF);

  const int tid = threadIdx.x;
  const int wid = tid >> 6;
  const int lane = tid & 63;
  const int ln16 = lane & 15;
  const int lq = lane >> 4;
  const int q8 = lq << 3;
  const int mg = wid >> 2;   // row half: 0/1
  const int sub = wid & 3;   // col slice / head

  const int wi = blockIdx.x;
  const int b = wi >> 8;
  const int rem = wi & 255;
  const int wy = rem >> 4, wx = rem & 15;
  const int xbase = ((b * 128 + wy * 8) * 128 + wx * 8) * 128;

  // ---- stage 2: GEMM1  qkv = X @ Wqkv + b  (A-fragments straight from global) ----
  f32x4 acc1[2][6];
  #pragma unroll
  for (int nt = 0; nt < 6; nt++) {
    float bv = qkvb[96 * sub + 16 * nt + ln16];
    f32x4 ci = {bv, bv, bv, bv};
    acc1[0][nt] = ci;
    acc1[1][nt] = ci;
  }

  #pragma unroll
  for (int ks = 0; ks < 4; ks++) {
    bf16x8 a0 = ldx(x, xbase, 32 * mg + ln16, 32 * ks + q8, isbf);
    bf16x8 a1 = ldx(x, xbase, 32 * mg + 16 + ln16, 32 * ks + q8, isbf);
    bf16x8 bb[6];
    #pragma unroll
    for (int nt = 0; nt < 6; nt++)
      bb[nt] = *(const bf16x8_a*)(wqkvT + (96 * sub + 16 * nt + ln16) * 128 + 32 * ks + q8);
    #pragma unroll
    for (int nt = 0; nt < 6; nt++) {
      acc1[0][nt] = __builtin_amdgcn_mfma_f32_16x16x32_bf16(a0, bb[nt], acc1[0][nt], 0, 0, 0);
      acc1[1][nt] = __builtin_amdgcn_mfma_f32_16x16x32_bf16(a1, bb[nt], acc1[1][nt], 0, 0, 0);
    }
  }

  // epilogue: per 32-col chunk -> q/k normalized rows (q pre-scaled), v transposed.
  // Q has its own LDS region now -> written immediately, no hold, no extra barrier.
  #pragma unroll
  for (int ci = 0; ci < 3; ci++) {
    int n0 = 96 * sub + 32 * ci;
    int type = n0 >> 7;              // 0=q 1=k 2=v
    int head = (n0 & 127) >> 5;
    int nt0 = 2 * ci, nt1 = nt0 + 1;
    if (type < 2) {
      int base = (type == 0) ? Q_OFF : K_OFF;
      float sh = (type == 0) ? scalef[head] : 1.0f;  // fold logit scale into q
      #pragma unroll
      for (int mt = 0; mt < 2; mt++)
        #pragma unroll
        for (int r = 0; r < 4; r++) {
          float x0 = acc1[mt][nt0][r], x1 = acc1[mt][nt1][r];
          float ss = x0 * x0 + x1 * x1;
          ss += __shfl_xor(ss, 1);
          ss += __shfl_xor(ss, 2);
          ss += __shfl_xor(ss, 4);
          ss += __shfl_xor(ss, 8);
          float inv = sh / fmaxf(sqrtf(ss), 1e-12f);
          int row = 32 * mg + 16 * mt + 4 * lq + r;
          lds[base + sw(row, head * 32 + ln16, 128)] = f2bf(x0 * inv);
          lds[base + sw(row, head * 32 + 16 + ln16, 128)] = f2bf(x1 * inv);
        }
    } else {
      #pragma unroll
      for (int mt = 0; mt < 2; mt++)
        #pragma unroll
        for (int r = 0; r < 4; r++) {
          int row = 32 * mg + 16 * mt + 4 * lq + r;
          lds[VT_OFF + sw(head * 32 + ln16, row, 64)] = f2bf(acc1[mt][nt0][r]);
          lds[VT_OFF + sw(head * 32 + 16 + ln16, row, 64)] = f2bf(acc1[mt][nt1][r]);
        }
    }
  }
  __syncthreads();  // B1: Q/K/VT visible

  // ---- stage 3: S^T = k.(q*scale)^T + (bias+mask)^T (as MFMA C), softmax ----
  // Swapped operands: A = K rows, B = Q rows -> C layout has q = lane&15 (col),
  // k = 4*lq + r (row). Softmax over k = in-reg reduce + xor16 + xor32.
  const int h = sub;
  bf16x8 kf[4], qf[2];
  #pragma unroll
  for (int kt = 0; kt < 4; kt++)
    kf[kt] = *(const bf16x8_a*)(lds + K_OFF + sw(16 * kt + ln16, h * 32 + q8, 128));
  #pragma unroll
  for (int qt = 0; qt < 2; qt++)
    qf[qt] = *(const bf16x8_a*)(lds + Q_OFF + sw(32 * mg + 16 * qt + ln16, h * 32 + q8, 128));

  // preload (bias+mask)^T as the MFMA C operand — k is the register axis, so
  // these are f32x4 / 8B vector loads (4 consecutive k per lane).
  const float* brow = bias16 + h * 4096;
  const u16* mk16 = (const u16*)mask;
  const float* mkf = (const float*)mask;
  f32x4 ST[4][2];
  #pragma unroll
  for (int qt = 0; qt < 2; qt++) {
    int q = 32 * mg + 16 * qt + ln16;
    #pragma unroll
    for (int kt = 0; kt < 4; kt++) {
      int bi = q * 64 + 16 * kt + 4 * lq;
      f32x4 bv = *(const f32x4_a*)(brow + bi);
      f32x4 cv;
      if (isbf) {
        u64_a mw = *(const u64_a*)(mk16 + rem * 4096 + bi);
        cv[0] = bv[0] + bf2f((u16)mw);
        cv[1] = bv[1] + bf2f((u16)(mw >> 16));
        cv[2] = bv[2] + bf2f((u16)(mw >> 32));
        cv[3] = bv[3] + bf2f((u16)(mw >> 48));
      } else {
        f32x4 mv = *(const f32x4_a*)(mkf + rem * 4096 + bi);
        cv = bv + mv;
      }
      ST[kt][qt] = cv;
    }
  }
  #pragma unroll
  for (int kt = 0; kt < 4; kt++)
    #pragma unroll
    for (int qt = 0; qt < 2; qt++)
      ST[kt][qt] = __builtin_amdgcn_mfma_f32_16x16x32_bf16(kf[kt], qf[qt], ST[kt][qt], 0, 0, 0);

  // softmax over k (rows of S^T): per q-column, 16 in-reg values + 2 shuffles
  #pragma unroll
  for (int qt = 0; qt < 2; qt++) {
    float m = ST[0][qt][0];
    #pragma unroll
    for (int kt = 0; kt < 4; kt++)
      #pragma unroll
      for (int r = 0; r < 4; r++) m = fmaxf(m, ST[kt][qt][r]);
    m = fmaxf(m, __shfl_xor(m, 16));
    m = fmaxf(m, __shfl_xor(m, 32));
    float sum = 0.f;
    #pragma unroll
    for (int kt = 0; kt < 4; kt++)
      #pragma unroll
      for (int r = 0; r < 4; r++) {
        float p = __expf(ST[kt][qt][r] - m);
        ST[kt][qt][r] = p;
        sum += p;
      }
    sum += __shfl_xor(sum, 16);
    sum += __shfl_xor(sum, 32);
    float inv = 1.0f / sum;
    #pragma unroll
    for (int kt = 0; kt < 4; kt++)
      #pragma unroll
      for (int r = 0; r < 4; r++) ST[kt][qt][r] *= inv;
  }
  __syncthreads();  // B2: everyone done reading Q/K before P overlays them

  // ---- stage 4/5: P -> LDS (8x 8B stores), O = P @ V ----
  // P[row=q][col=h*64+k]: lane holds q=ln16-based col, k=4lq+r rows -> 4
  // consecutive k land in one swizzle block -> pack 2 words, one 8B store.
  #pragma unroll
  for (int qt = 0; qt < 2; qt++)
    #pragma unroll
    for (int kt = 0; kt < 4; kt++) {
      int row = 32 * mg + 16 * qt + ln16;
      int col = h * 64 + 16 * kt + 4 * lq;
      unsigned int w0 = (unsigned int)f2bf(ST[kt][qt][0]) | ((unsigned int)f2bf(ST[kt][qt][1]) << 16);
      unsigned int w1 = (unsigned int)f2bf(ST[kt][qt][2]) | ((unsigned int)f2bf(ST[kt][qt][3]) << 16);
      i32x2 wv = {(int)w0, (int)w1};
      *(i32x2_a*)(lds + P_OFF + sw(row, col, 256)) = wv;
    }
  __syncthreads();  // B3: P visible
  f32x4 O[2][2];
  O[0][0] = fz; O[0][1] = fz; O[1][0] = fz; O[1][1] = fz;
  #pragma unroll
  for (int ks = 0; ks < 2; ks++) {
    bf16x8 pf[2], vf[2];
    #pragma unroll
    for (int mt = 0; mt < 2; mt++)
      pf[mt] = *(const bf16x8_a*)(lds + P_OFF + sw(32 * mg + 16 * mt + ln16, h * 64 + 32 * ks + q8, 256));
    #pragma unroll
    for (int nt = 0; nt < 2; nt++)
      vf[nt] = *(const bf16x8_a*)(lds + VT_OFF + sw(h * 32 + 16 * nt + ln16, 32 * ks + q8, 64));
    #pragma unroll
    for (int mt = 0; mt < 2; mt++)
      #pragma unroll
      for (int nt = 0; nt < 2; nt++)
        O[mt][nt] = __builtin_amdgcn_mfma_f32_16x16x32_bf16(pf[mt], vf[nt], O[mt][nt], 0, 0, 0);
  }
  __syncthreads();  // B4: all waves done reading P before AO overlays it
  #pragma unroll
  for (int mt = 0; mt < 2; mt++)
    #pragma unroll
    for (int nt = 0; nt < 2; nt++)
      #pragma unroll
      for (int r = 0; r < 4; r++) {
        int row = 32 * mg + 16 * mt + 4 * lq + r;
        lds[AO_OFF + sw(row, h * 32 + 16 * nt + ln16, 128)] = f2bf(O[mt][nt][r]);
      }
  __syncthreads();  // B5: AO visible

  // ---- stage 6: out = AO @ proj_w + proj_b (bias folded into C init) ----
  float pb0 = pbf[32 * sub + ln16];
  float pb1 = pbf[32 * sub + 16 + ln16];
  f32x4 acc3[2][2];
  {
    f32x4 c0 = {pb0, pb0, pb0, pb0};
    f32x4 c1 = {pb1, pb1, pb1, pb1};
    acc3[0][0] = c0; acc3[0][1] = c1; acc3[1][0] = c0; acc3[1][1] = c1;
  }
  #pragma unroll
  for (int ks = 0; ks < 4; ks++) {
    bf16x8 a0 = *(const bf16x8_a*)(lds + AO_OFF + sw(32 * mg + ln16, 32 * ks + q8, 128));
    bf16x8 a1 = *(const bf16x8_a*)(lds + AO_OFF + sw(32 * mg + 16 + ln16, 32 * ks + q8, 128));
    bf16x8 b0 = *(const bf16x8_a*)(pwT + (32 * sub + ln16) * 128 + 32 * ks + q8);
    bf16x8 b1 = *(const bf16x8_a*)(pwT + (32 * sub + 16 + ln16) * 128 + 32 * ks + q8);
    acc3[0][0] = __builtin_amdgcn_mfma_f32_16x16x32_bf16(a0, b0, acc3[0][0], 0, 0, 0);
    acc3[0][1] = __builtin_amdgcn_mfma_f32_16x16x32_bf16(a0, b1, acc3[0][1], 0, 0, 0);
    acc3[1][0] = __builtin_amdgcn_mfma_f32_16x16x32_bf16(a1, b0, acc3[1][0], 0, 0, 0);
    acc3[1][1] = __builtin_amdgcn_mfma_f32_16x16x32_bf16(a1, b1, acc3[1][1], 0, 0, 0);
  }
  if (isbf) {
    u16* ob = (u16*)out;
    #pragma unroll
    for (int mt = 0; mt < 2; mt++)
      #pragma unroll
      for (int r = 0; r < 4; r++) {
        int row = 32 * mg + 16 * mt + 4 * lq + r;
        int o = xbase + (row >> 3) * 16384 + (row & 7) * 128 + 32 * sub;
        ob[o + ln16] = f2bf(acc3[mt][0][r]);
        ob[o + 16 + ln16] = f2bf(acc3[mt][1][r]);
      }
  } else {
    float* of = (float*)out;
    #pragma unroll
    for (int mt = 0; mt < 2; mt++)
      #pragma unroll
      for (int r = 0; r < 4; r++) {
        int row = 32 * mg + 16 * mt + 4 * lq + r;
        int o = xbase + (row >> 3) * 16384 + (row & 7) * 128 + 32 * sub;
        of[o + ln16] = acc3[mt][0][r];
        of[o + 16 + ln16] = acc3[mt][1][r];
      }
  }
}

extern "C" void kernel_launch(void* const* d_in, const int* in_sizes, int n_in,
                              void* d_out, int out_size, void* d_ws, size_t ws_size,
                              hipStream_t stream) {
  const void* x      = d_in[0];
  const void* mask   = d_in[1];
  const void* qkv_w  = d_in[2];
  const void* q_bias = d_in[3];
  const void* v_bias = d_in[4];
  const void* ls     = d_in[5];
  const void* cpb_w1 = d_in[6];
  const void* cpb_b1 = d_in[7];
  const void* cpb_w2 = d_in[8];
  const void* proj_w = d_in[9];
  const void* proj_b = d_in[10];
  const int B = in_sizes[0] / (128 * 128 * 128);

  char* ws = (char*)d_ws;
  swin_detect<<<1, 64, 0, stream>>>((const unsigned int*)x,
                                    (unsigned int*)(ws + FLAG_OFF));
  swin_setup<<<258, 256, 0, stream>>>(qkv_w, q_bias, v_bias, ls, cpb_w1, cpb_b1,
                                      cpb_w2, proj_w, proj_b, ws);
  swin_main<<<B * 256, 512, 0, stream>>>(x, mask, ws, d_out);
}

// Round 5
// 455.507 us; speedup vs baseline: 1.0983x; 1.0862x over previous
//
#include <hip/hip_runtime.h>

typedef unsigned short u16;
typedef __bf16 bf16x8 __attribute__((ext_vector_type(8)));
typedef float f32x4 __attribute__((ext_vector_type(4)));
typedef int i32x4 __attribute__((ext_vector_type(4)));
typedef int i32x2 __attribute__((ext_vector_type(2)));
// may_alias: LDS/global buffers are accessed as u16, i32x2/4, f32x4 and bf16x8 —
// without this, TBAA lets the compiler reorder the P-matrix stores vs loads.
typedef i32x4 i32x4_a __attribute__((may_alias));
typedef i32x2 i32x2_a __attribute__((may_alias));
typedef bf16x8 bf16x8_a __attribute__((may_alias));
typedef f32x4 f32x4_a __attribute__((may_alias));
typedef unsigned long long u64_a __attribute__((may_alias));

__device__ __forceinline__ float bf2f(u16 u) {
  union { unsigned int i; float f; } c;
  c.i = ((unsigned int)u) << 16;
  return c.f;
}
// Native cast -> v_cvt_pk_bf16_f32 (RNE) instead of 4-5 op software RNE.
__device__ __forceinline__ u16 f2bf(float f) {
  union { __bf16 h; u16 u; } c;
  c.h = (__bf16)f;
  return c.u;
}
// dual-dtype scalar load: isbf ? bf16[i] : f32[i]
__device__ __forceinline__ float gld(const void* p, int i, int isbf) {
  return isbf ? bf2f(((const u16*)p)[i]) : ((const float*)p)[i];
}
// XOR-swizzled LDS element offset (16B blocks swizzled by row low 3 bits).
__device__ __forceinline__ int sw(int row, int col, int rs) {
  return row * rs + ((((col >> 3) ^ (row & 7)) << 3) | (col & 7));
}

// ws layout (bytes):
//   0      : wqkvT  bf16 [384][128]   (98304)
//   98304  : pwT    bf16 [128][128]   (32768)
//   131072 : qkvb   f32  [384]        (1536)
//   132608 : bias16 f32  [4][64][64]  (65536)  == 16*sigmoid(cpb MLP)[h][q][k]
//   198144 : scalef f32  [4]          (16)     == exp(min(logit_scale, ln100))
//   198160 : pbf    f32  [128]        (512)
//   198672 : flag   u32  (1=bf16 inputs, 0=f32 inputs)
#define WQKVT_OFF 0
#define PWT_OFF   98304
#define QKVB_OFF  131072
#define BIAS_OFF  132608
#define SCALE_OFF 198144
#define PB_OFF    198160
#define FLAG_OFF  198672

// ---------------- dtype probe ----------------
__global__ void swin_detect(const unsigned int* __restrict__ xw,
                            unsigned int* __restrict__ flag) {
  int t = threadIdx.x;  // 64 threads
  int cnt = 0;
  for (int i = 0; i < 8; i++) {
    unsigned int w = xw[t * 8 + i];
    unsigned int lo = w & 0xffffu;
    unsigned int e = (lo >> 7) & 0xffu;
    if ((e >= 0x70u && e <= 0x82u) || lo == 0u) cnt++;
  }
  cnt += __shfl_xor(cnt, 1);
  cnt += __shfl_xor(cnt, 2);
  cnt += __shfl_xor(cnt, 4);
  cnt += __shfl_xor(cnt, 8);
  cnt += __shfl_xor(cnt, 16);
  cnt += __shfl_xor(cnt, 32);
  if (t == 0) *flag = (cnt >= 256) ? 1u : 0u;
}

// ---------------- setup v2 ----------------
__global__ void swin_setup(const void* __restrict__ qkv_w, const void* __restrict__ q_bias,
                           const void* __restrict__ v_bias, const void* __restrict__ ls,
                           const void* __restrict__ cpb_w1, const void* __restrict__ cpb_b1,
                           const void* __restrict__ cpb_w2, const void* __restrict__ proj_w,
                           const void* __restrict__ proj_b, char* __restrict__ ws) {
  const int b = blockIdx.x, t = threadIdx.x;
  const int isbf = (int)*(const unsigned int*)(ws + FLAG_OFF);
  u16* wqkvT = (u16*)(ws + WQKVT_OFF);
  u16* pwT = (u16*)(ws + PWT_OFF);
  float* qkvb = (float*)(ws + QKVB_OFF);
  float* bias16 = (float*)(ws + BIAS_OFF);
  float* scalef = (float*)(ws + SCALE_OFF);
  float* pbf = (float*)(ws + PB_OFF);

  if (b < 128) {           // qkv_w row b: coalesced read, scattered write
    for (int c = t; c < 384; c += 256)
      wqkvT[c * 128 + b] = f2bf(gld(qkv_w, b * 384 + c, isbf));
  } else if (b < 256) {    // proj_w row (b-128)
    int r = b - 128;
    if (t < 128) pwT[t * 128 + r] = f2bf(gld(proj_w, r * 128 + t, isbf));
  } else if (b == 256) {   // small vectors
    for (int o = t; o < 384; o += 256) {
      float v = 0.f;
      if (o < 128) v = gld(q_bias, o, isbf);
      else if (o >= 256) v = gld(v_bias, o - 256, isbf);
      qkvb[o] = v;
    }
    if (t < 128) pbf[t] = gld(proj_b, t, isbf);
    if (t < 4) scalef[t] = expf(fminf(gld(ls, t, isbf), 4.60517019f));
  } else {                 // CPB MLP -> 16*sigmoid, gathered by rel-pos index
    __shared__ float w1[1024];   // [2][512]
    __shared__ float b1[512];
    __shared__ float w2[2048];   // [512][4]
    __shared__ float tab[225][4];
    for (int i = t; i < 1024; i += 256) w1[i] = gld(cpb_w1, i, isbf);
    for (int i = t; i < 512; i += 256) b1[i] = gld(cpb_b1, i, isbf);
    for (int i = t; i < 2048; i += 256) w2[i] = gld(cpb_w2, i, isbf);
    __syncthreads();
    if (t < 225) {
      int i = t / 15, j = t % 15;
      float c0, c1;
      {
        float tt = ((float)(i - 7) / 7.0f) * 8.0f;
        float s = (tt > 0.f) ? 1.f : ((tt < 0.f) ? -1.f : 0.f);
        c0 = s * log2f(fabsf(tt) + 1.f) / 3.0f;
      }
      {
        float tt = ((float)(j - 7) / 7.0f) * 8.0f;
        float s = (tt > 0.f) ? 1.f : ((tt < 0.f) ? -1.f : 0.f);
        c1 = s * log2f(fabsf(tt) + 1.f) / 3.0f;
      }
      float acc[4] = {0.f, 0.f, 0.f, 0.f};
      for (int jj = 0; jj < 512; jj++) {
        float h = fmaxf(c0 * w1[jj] + c1 * w1[512 + jj] + b1[jj], 0.f);
        #pragma unroll
        for (int hh = 0; hh < 4; hh++) acc[hh] += h * w2[jj * 4 + hh];
      }
      #pragma unroll
      for (int hh = 0; hh < 4; hh++) tab[t][hh] = acc[hh];
    }
    __syncthreads();
    for (int e = t; e < 4 * 64 * 64; e += 256) {
      int h = e >> 12, q = (e >> 6) & 63, kk = e & 63;
      int dr = (q >> 3) - (kk >> 3) + 7;
      int dc = (q & 7) - (kk & 7) + 7;
      float v = tab[dr * 15 + dc][h];
      bias16[e] = 16.f / (1.f + expf(-v));
    }
  }
}

// ---------------- fused per-window kernel (round-7) ----------------
// One block per window (B*256 blocks), 512 threads = 8 waves.
// Round-7 post-mortem of round-6 (305us): dropping X LDS staging made GEMM1
//   A-loads a per-lane ROW GATHER (16 lanes x 16B at 256B stride = ~64 cache
//   lines per VMEM instr vs 4 coalesced) -> VMEM pipe clogged in front of
//   dependent MFMAs. VALUBusy 43->29 (more stall). FETCH unchanged (~73MB,
//   L1/L2 absorbed) — a latency cost, not BW. ~+55us.
// Round-7 = union of measured-good pieces only:
//   - X staged to LDS coalesced (rounds 2/4: best).
//   - round-6's stage 3 kept: swapped S^T=mfma(K,Q), softmax = in-reg + 2
//     shuffles (vs 64), vectorized bias+mask C-init, 8B packed P stores.
//   - 64KB LDS, ALL REGIONS DISJOINT -> 5 barriers (vs round-4's 7): Q no
//     longer overlays X (no post-GEMM1-read barrier, no reg-holding); AO
//     overlays dead K (no pre-AO barrier: disjoint from P/VT being read).
//   - V^T epilogue stores packed i32x2 (4 stores vs 16 scalar).
//   Occupancy stays 2 blocks/CU (reg-walled: total arch+acc ~112/wave; 6
//   waves/SIMD needs <=85 and spills — proven rounds 3/5). (512,4) = the
//   proven no-spill config.
// LDS (u16 elements, 32768 total = 64KB):
//   X [0,8192)  Q [8192,16384)  K [16384,24576)  VT [24576,32768)
//   P overlays [0,16384) (X+Q, both dead);  AO overlays [16384,24576) (K, dead)
#define X_OFF 0
#define Q_OFF 8192
#define K_OFF 16384
#define VT_OFF 24576
#define P_OFF 0
#define AO_OFF 16384

__global__ __launch_bounds__(512, 4) void swin_main(
    const void* __restrict__ x, const void* __restrict__ mask,
    const char* __restrict__ ws, void* __restrict__ out) {
  __shared__ __align__(16) u16 lds[32768];
  const f32x4 fz = {0.f, 0.f, 0.f, 0.f};

  const u16* wqkvT = (const u16*)(ws + WQKVT_OFF);
  const u16* pwT = (const u16*)(ws + PWT_OFF);
  const float* qkvb = (const float*)(ws + QKVB_OFF);
  const float* bias16 = (const float*)(ws + BIAS_OFF);
  const float* scalef = (const float*)(ws + SCALE_OFF);
  const float* pbf = (const float*)(ws + PB_OFF);
  const int isbf = (int)*(const unsigned int*)(ws + FLAG_OFF);

  const int tid = threadIdx.x;
  const int wid = tid >> 6;
  const int lane = tid & 63;
  const int ln16 = lane & 15;
  const int lq = lane >> 4;
  const int q8 = lq << 3;
  const int mg = wid >> 2;   // row half: 0/1
  const int sub = wid & 3;   // col slice / head

  const int wi = blockIdx.x;
  const int b = wi >> 8;
  const int rem = wi & 255;
  const int wy = rem >> 4, wx = rem & 15;
  const int xbase = ((b * 128 + wy * 8) * 128 + wx * 8) * 128;

  // ---- stage 1: X tile -> LDS as bf16 (coalesced) ----
  if (isbf) {
    const u16* xb = (const u16*)x;
    #pragma unroll
    for (int rep = 0; rep < 2; rep++) {
      int ch = tid + rep * 512;          // 1024 chunks of 8 elements
      int token = ch >> 4, dch = ch & 15;
      int r = token >> 3, c = token & 7;
      i32x4 v = *(const i32x4_a*)(xb + xbase + r * 16384 + c * 128 + dch * 8);
      *(i32x4_a*)(lds + X_OFF + sw(token, dch * 8, 128)) = v;
    }
  } else {
    const float* xf = (const float*)x;
    #pragma unroll
    for (int rep = 0; rep < 2; rep++) {
      int ch = tid + rep * 512;
      int token = ch >> 4, dch = ch & 15;
      int r = token >> 3, c = token & 7;
      const float* src = xf + xbase + r * 16384 + c * 128 + dch * 8;
      union { i32x4 v2[2]; float f[8]; } in;
      in.v2[0] = *(const i32x4_a*)(src);
      in.v2[1] = *(const i32x4_a*)(src + 4);
      union { u16 u[8]; i32x4 v; } o;
      #pragma unroll
      for (int d = 0; d < 8; d++) o.u[d] = f2bf(in.f[d]);
      *(i32x4_a*)(lds + X_OFF + sw(token, dch * 8, 128)) = o.v;
    }
  }
  __syncthreads();  // B0: X visible

  // ---- stage 2: GEMM1  qkv = X @ Wqkv + b  (bias folded into C init) ----
  f32x4 acc1[2][6];
  #pragma unroll
  for (int nt = 0; nt < 6; nt++) {
    float bv = qkvb[96 * sub + 16 * nt + ln16];
    f32x4 ci = {bv, bv, bv, bv};
    acc1[0][nt] = ci;
    acc1[1][nt] = ci;
  }

  #pragma unroll
  for (int ks = 0; ks < 4; ks++) {
    bf16x8 a0 = *(const bf16x8_a*)(lds + X_OFF + sw(32 * mg + ln16, 32 * ks + q8, 128));
    bf16x8 a1 = *(const bf16x8_a*)(lds + X_OFF + sw(32 * mg + 16 + ln16, 32 * ks + q8, 128));
    bf16x8 bb[6];
    #pragma unroll
    for (int nt = 0; nt < 6; nt++)
      bb[nt] = *(const bf16x8_a*)(wqkvT + (96 * sub + 16 * nt + ln16) * 128 + 32 * ks + q8);
    #pragma unroll
    for (int nt = 0; nt < 6; nt++) {
      acc1[0][nt] = __builtin_amdgcn_mfma_f32_16x16x32_bf16(a0, bb[nt], acc1[0][nt], 0, 0, 0);
      acc1[1][nt] = __builtin_amdgcn_mfma_f32_16x16x32_bf16(a1, bb[nt], acc1[1][nt], 0, 0, 0);
    }
  }

  // epilogue: per 32-col chunk -> q/k normalized rows (q pre-scaled) written
  // to their own disjoint LDS regions immediately; v transposed + packed.
  #pragma unroll
  for (int ci = 0; ci < 3; ci++) {
    int n0 = 96 * sub + 32 * ci;
    int type = n0 >> 7;              // 0=q 1=k 2=v
    int head = (n0 & 127) >> 5;
    int nt0 = 2 * ci, nt1 = nt0 + 1;
    if (type < 2) {
      int base = (type == 0) ? Q_OFF : K_OFF;
      float sh = (type == 0) ? scalef[head] : 1.0f;  // fold logit scale into q
      #pragma unroll
      for (int mt = 0; mt < 2; mt++)
        #pragma unroll
        for (int r = 0; r < 4; r++) {
          float x0 = acc1[mt][nt0][r], x1 = acc1[mt][nt1][r];
          float ss = x0 * x0 + x1 * x1;
          ss += __shfl_xor(ss, 1);
          ss += __shfl_xor(ss, 2);
          ss += __shfl_xor(ss, 4);
          ss += __shfl_xor(ss, 8);
          float inv = sh / fmaxf(sqrtf(ss), 1e-12f);
          int row = 32 * mg + 16 * mt + 4 * lq + r;
          lds[base + sw(row, head * 32 + ln16, 128)] = f2bf(x0 * inv);
          lds[base + sw(row, head * 32 + 16 + ln16, 128)] = f2bf(x1 * inv);
        }
    } else {
      // v: transposed, packed — 4 consecutive cols (tokens) per lane -> i32x2
      #pragma unroll
      for (int mt = 0; mt < 2; mt++) {
        int c0 = 32 * mg + 16 * mt + 4 * lq;
        unsigned int w0 = (unsigned int)f2bf(acc1[mt][nt0][0]) | ((unsigned int)f2bf(acc1[mt][nt0][1]) << 16);
        unsigned int w1 = (unsigned int)f2bf(acc1[mt][nt0][2]) | ((unsigned int)f2bf(acc1[mt][nt0][3]) << 16);
        i32x2 wv = {(int)w0, (int)w1};
        *(i32x2_a*)(lds + VT_OFF + sw(head * 32 + ln16, c0, 64)) = wv;
        unsigned int u0 = (unsigned int)f2bf(acc1[mt][nt1][0]) | ((unsigned int)f2bf(acc1[mt][nt1][1]) << 16);
        unsigned int u1 = (unsigned int)f2bf(acc1[mt][nt1][2]) | ((unsigned int)f2bf(acc1[mt][nt1][3]) << 16);
        i32x2 uv = {(int)u0, (int)u1};
        *(i32x2_a*)(lds + VT_OFF + sw(head * 32 + 16 + ln16, c0, 64)) = uv;
      }
    }
  }
  __syncthreads();  // B1: Q/K/VT visible (and all X reads done)

  // ---- stage 3: S^T = k.(q*scale)^T + (bias+mask)^T (as MFMA C), softmax ----
  // Swapped operands: A = K rows, B = Q rows -> C layout has q = lane&15 (col),
  // k = 4*lq + r (row). Softmax over k = in-reg reduce + xor16 + xor32.
  const int h = sub;
  bf16x8 kf[4], qf[2];
  #pragma unroll
  for (int kt = 0; kt < 4; kt++)
    kf[kt] = *(const bf16x8_a*)(lds + K_OFF + sw(16 * kt + ln16, h * 32 + q8, 128));
  #pragma unroll
  for (int qt = 0; qt < 2; qt++)
    qf[qt] = *(const bf16x8_a*)(lds + Q_OFF + sw(32 * mg + 16 * qt + ln16, h * 32 + q8, 128));

  // preload (bias+mask)^T as the MFMA C operand — k is the register axis, so
  // these are f32x4 / 8B vector loads (4 consecutive k per lane).
  const float* brow = bias16 + h * 4096;
  const u16* mk16 = (const u16*)mask;
  const float* mkf = (const float*)mask;
  f32x4 ST[4][2];
  #pragma unroll
  for (int qt = 0; qt < 2; qt++) {
    int q = 32 * mg + 16 * qt + ln16;
    #pragma unroll
    for (int kt = 0; kt < 4; kt++) {
      int bi = q * 64 + 16 * kt + 4 * lq;
      f32x4 bv = *(const f32x4_a*)(brow + bi);
      f32x4 cv;
      if (isbf) {
        u64_a mw = *(const u64_a*)(mk16 + rem * 4096 + bi);
        cv[0] = bv[0] + bf2f((u16)mw);
        cv[1] = bv[1] + bf2f((u16)(mw >> 16));
        cv[2] = bv[2] + bf2f((u16)(mw >> 32));
        cv[3] = bv[3] + bf2f((u16)(mw >> 48));
      } else {
        f32x4 mv = *(const f32x4_a*)(mkf + rem * 4096 + bi);
        cv = bv + mv;
      }
      ST[kt][qt] = cv;
    }
  }
  #pragma unroll
  for (int kt = 0; kt < 4; kt++)
    #pragma unroll
    for (int qt = 0; qt < 2; qt++)
      ST[kt][qt] = __builtin_amdgcn_mfma_f32_16x16x32_bf16(kf[kt], qf[qt], ST[kt][qt], 0, 0, 0);

  // softmax over k (rows of S^T): per q-column, 16 in-reg values + 2 shuffles
  #pragma unroll
  for (int qt = 0; qt < 2; qt++) {
    float m = ST[0][qt][0];
    #pragma unroll
    for (int kt = 0; kt < 4; kt++)
      #pragma unroll
      for (int r = 0; r < 4; r++) m = fmaxf(m, ST[kt][qt][r]);
    m = fmaxf(m, __shfl_xor(m, 16));
    m = fmaxf(m, __shfl_xor(m, 32));
    float sum = 0.f;
    #pragma unroll
    for (int kt = 0; kt < 4; kt++)
      #pragma unroll
      for (int r = 0; r < 4; r++) {
        float p = __expf(ST[kt][qt][r] - m);
        ST[kt][qt][r] = p;
        sum += p;
      }
    sum += __shfl_xor(sum, 16);
    sum += __shfl_xor(sum, 32);
    float inv = 1.0f / sum;
    #pragma unroll
    for (int kt = 0; kt < 4; kt++)
      #pragma unroll
      for (int r = 0; r < 4; r++) ST[kt][qt][r] *= inv;
  }
  __syncthreads();  // B2: all Q/K reads done before P overlays X+Q

  // ---- stage 4/5: P -> LDS (8x 8B stores), O = P @ V ----
  // P[row=q][col=h*64+k]: lane holds q=ln16-based col, k=4lq+r rows -> 4
  // consecutive k land in one swizzle block -> pack 2 words, one 8B store.
  #pragma unroll
  for (int qt = 0; qt < 2; qt++)
    #pragma unroll
    for (int kt = 0; kt < 4; kt++) {
      int row = 32 * mg + 16 * qt + ln16;
      int col = h * 64 + 16 * kt + 4 * lq;
      unsigned int w0 = (unsigned int)f2bf(ST[kt][qt][0]) | ((unsigned int)f2bf(ST[kt][qt][1]) << 16);
      unsigned int w1 = (unsigned int)f2bf(ST[kt][qt][2]) | ((unsigned int)f2bf(ST[kt][qt][3]) << 16);
      i32x2 wv = {(int)w0, (int)w1};
      *(i32x2_a*)(lds + P_OFF + sw(row, col, 256)) = wv;
    }
  __syncthreads();  // B3: P visible
  f32x4 O[2][2];
  O[0][0] = fz; O[0][1] = fz; O[1][0] = fz; O[1][1] = fz;
  #pragma unroll
  for (int ks = 0; ks < 2; ks++) {
    bf16x8 pf[2], vf[2];
    #pragma unroll
    for (int mt = 0; mt < 2; mt++)
      pf[mt] = *(const bf16x8_a*)(lds + P_OFF + sw(32 * mg + 16 * mt + ln16, h * 64 + 32 * ks + q8, 256));
    #pragma unroll
    for (int nt = 0; nt < 2; nt++)
      vf[nt] = *(const bf16x8_a*)(lds + VT_OFF + sw(h * 32 + 16 * nt + ln16, 32 * ks + q8, 64));
    #pragma unroll
    for (int mt = 0; mt < 2; mt++)
      #pragma unroll
      for (int nt = 0; nt < 2; nt++)
        O[mt][nt] = __builtin_amdgcn_mfma_f32_16x16x32_bf16(pf[mt], vf[nt], O[mt][nt], 0, 0, 0);
  }
  // AO region (old K) is disjoint from P and VT -> store immediately, no barrier
  #pragma unroll
  for (int mt = 0; mt < 2; mt++)
    #pragma unroll
    for (int nt = 0; nt < 2; nt++)
      #pragma unroll
      for (int r = 0; r < 4; r++) {
        int row = 32 * mg + 16 * mt + 4 * lq + r;
        lds[AO_OFF + sw(row, h * 32 + 16 * nt + ln16, 128)] = f2bf(O[mt][nt][r]);
      }
  __syncthreads();  // B4: AO visible

  // ---- stage 6: out = AO @ proj_w + proj_b (bias folded into C init) ----
  float pb0 = pbf[32 * sub + ln16];
  float pb1 = pbf[32 * sub + 16 + ln16];
  f32x4 acc3[2][2];
  {
    f32x4 c0 = {pb0, pb0, pb0, pb0};
    f32x4 c1 = {pb1, pb1, pb1, pb1};
    acc3[0][0] = c0; acc3[0][1] = c1; acc3[1][0] = c0; acc3[1][1] = c1;
  }
  #pragma unroll
  for (int ks = 0; ks < 4; ks++) {
    bf16x8 a0 = *(const bf16x8_a*)(lds + AO_OFF + sw(32 * mg + ln16, 32 * ks + q8, 128));
    bf16x8 a1 = *(const bf16x8_a*)(lds + AO_OFF + sw(32 * mg + 16 + ln16, 32 * ks + q8, 128));
    bf16x8 b0 = *(const bf16x8_a*)(pwT + (32 * sub + ln16) * 128 + 32 * ks + q8);
    bf16x8 b1 = *(const bf16x8_a*)(pwT + (32 * sub + 16 + ln16) * 128 + 32 * ks + q8);
    acc3[0][0] = __builtin_amdgcn_mfma_f32_16x16x32_bf16(a0, b0, acc3[0][0], 0, 0, 0);
    acc3[0][1] = __builtin_amdgcn_mfma_f32_16x16x32_bf16(a0, b1, acc3[0][1], 0, 0, 0);
    acc3[1][0] = __builtin_amdgcn_mfma_f32_16x16x32_bf16(a1, b0, acc3[1][0], 0, 0, 0);
    acc3[1][1] = __builtin_amdgcn_mfma_f32_16x16x32_bf16(a1, b1, acc3[1][1], 0, 0, 0);
  }
  if (isbf) {
    u16* ob = (u16*)out;
    #pragma unroll
    for (int mt = 0; mt < 2; mt++)
      #pragma unroll
      for (int r = 0; r < 4; r++) {
        int row = 32 * mg + 16 * mt + 4 * lq + r;
        int o = xbase + (row >> 3) * 16384 + (row & 7) * 128 + 32 * sub;
        ob[o + ln16] = f2bf(acc3[mt][0][r]);
        ob[o + 16 + ln16] = f2bf(acc3[mt][1][r]);
      }
  } else {
    float* of = (float*)out;
    #pragma unroll
    for (int mt = 0; mt < 2; mt++)
      #pragma unroll
      for (int r = 0; r < 4; r++) {
        int row = 32 * mg + 16 * mt + 4 * lq + r;
        int o = xbase + (row >> 3) * 16384 + (row & 7) * 128 + 32 * sub;
        of[o + ln16] = acc3[mt][0][r];
        of[o + 16 + ln16] = acc3[mt][1][r];
      }
  }
}

extern "C" void kernel_launch(void* const* d_in, const int* in_sizes, int n_in,
                              void* d_out, int out_size, void* d_ws, size_t ws_size,
                              hipStream_t stream) {
  const void* x      = d_in[0];
  const void* mask   = d_in[1];
  const void* qkv_w  = d_in[2];
  const void* q_bias = d_in[3];
  const void* v_bias = d_in[4];
  const void* ls     = d_in[5];
  const void* cpb_w1 = d_in[6];
  const void* cpb_b1 = d_in[7];
  const void* cpb_w2 = d_in[8];
  const void* proj_w = d_in[9];
  const void* proj_b = d_in[10];
  const int B = in_sizes[0] / (128 * 128 * 128);

  char* ws = (char*)d_ws;
  swin_detect<<<1, 64, 0, stream>>>((const unsigned int*)x,
                                    (unsigned int*)(ws + FLAG_OFF));
  swin_setup<<<258, 256, 0, stream>>>(qkv_w, q_bias, v_bias, ls, cpb_w1, cpb_b1,
                                      cpb_w2, proj_w, proj_b, ws);
  swin_main<<<B * 256, 512, 0, stream>>>(x, mask, ws, d_out);
}

// Round 6
// 372.983 us; speedup vs baseline: 1.3413x; 1.2213x over previous
//
#include <hip/hip_runtime.h>

typedef unsigned short u16;
typedef __bf16 bf16x8 __attribute__((ext_vector_type(8)));
typedef float f32x4 __attribute__((ext_vector_type(4)));
typedef int i32x4 __attribute__((ext_vector_type(4)));
typedef int i32x2 __attribute__((ext_vector_type(2)));
// may_alias: LDS/global buffers are accessed as u16, i32x2/4, f32x4 and bf16x8 —
// without this, TBAA lets the compiler reorder the P-matrix stores vs loads.
typedef i32x4 i32x4_a __attribute__((may_alias));
typedef i32x2 i32x2_a __attribute__((may_alias));
typedef bf16x8 bf16x8_a __attribute__((may_alias));
typedef f32x4 f32x4_a __attribute__((may_alias));
typedef unsigned long long u64_a __attribute__((may_alias));

__device__ __forceinline__ float bf2f(u16 u) {
  union { unsigned int i; float f; } c;
  c.i = ((unsigned int)u) << 16;
  return c.f;
}
// Native cast -> v_cvt_pk_bf16_f32 (RNE).
__device__ __forceinline__ u16 f2bf(float f) {
  union { __bf16 h; u16 u; } c;
  c.h = (__bf16)f;
  return c.u;
}
// dual-dtype scalar load: isbf ? bf16[i] : f32[i]
__device__ __forceinline__ float gld(const void* p, int i, int isbf) {
  return isbf ? bf2f(((const u16*)p)[i]) : ((const float*)p)[i];
}
// XOR-swizzled LDS element offset (16B blocks swizzled by row low 3 bits).
__device__ __forceinline__ int sw(int row, int col, int rs) {
  return row * rs + ((((col >> 3) ^ (row & 7)) << 3) | (col & 7));
}

// ws layout (bytes):  [ROUND-8: wqkvF/pwF/bias16F are FRAGMENT-ORDER layouts]
//   0      : wqkvF  bf16 [4sub][6nt][4ks][64lane][8]  (98304)
//   98304  : pwF    bf16 [4sub][2nt][4ks][64lane][8]  (32768)
//   131072 : qkvb   f32  [384]        (1536)
//   132608 : bias16F f32 [4h][2mg][2qt][4kt][64lane][4r] (65536)
//   198144 : scalef f32  [4]          (16)     == exp(min(logit_scale, ln100))
//   198160 : pbf    f32  [128]        (512)
//   198672 : flag   u32  (1=bf16 inputs, 0=f32 inputs)
#define WQKVT_OFF 0
#define PWT_OFF   98304
#define QKVB_OFF  131072
#define BIAS_OFF  132608
#define SCALE_OFF 198144
#define PB_OFF    198160
#define FLAG_OFF  198672

// ---------------- dtype probe ----------------
__global__ void swin_detect(const unsigned int* __restrict__ xw,
                            unsigned int* __restrict__ flag) {
  int t = threadIdx.x;  // 64 threads
  int cnt = 0;
  for (int i = 0; i < 8; i++) {
    unsigned int w = xw[t * 8 + i];
    unsigned int lo = w & 0xffffu;
    unsigned int e = (lo >> 7) & 0xffu;
    if ((e >= 0x70u && e <= 0x82u) || lo == 0u) cnt++;
  }
  cnt += __shfl_xor(cnt, 1);
  cnt += __shfl_xor(cnt, 2);
  cnt += __shfl_xor(cnt, 4);
  cnt += __shfl_xor(cnt, 8);
  cnt += __shfl_xor(cnt, 16);
  cnt += __shfl_xor(cnt, 32);
  if (t == 0) *flag = (cnt >= 256) ? 1u : 0u;
}

// ---------------- setup v3: fragment-order weight layouts ----------------
// Round-8: swin_main's B-operand loads were 256B-stride row gathers (lane ln16
// indexes the row) — ~16 cache lines per 16B/lane load, 32 such instrs/wave,
// repeated by all 4096 blocks from L2 (128KB weights > 32KB L1). This was
// invariant across rounds 2-7 == the 248-267us plateau floor (same pattern
// that cost round-6 +55us on X). Fix: store weights/bias in FRAGMENT ORDER so
// each MFMA fragment load is base + const + lane*16B (coalesced, L1-friendly).
__global__ void swin_setup(const void* __restrict__ qkv_w, const void* __restrict__ q_bias,
                           const void* __restrict__ v_bias, const void* __restrict__ ls,
                           const void* __restrict__ cpb_w1, const void* __restrict__ cpb_b1,
                           const void* __restrict__ cpb_w2, const void* __restrict__ proj_w,
                           const void* __restrict__ proj_b, char* __restrict__ ws) {
  const int b = blockIdx.x, t = threadIdx.x;
  const int isbf = (int)*(const unsigned int*)(ws + FLAG_OFF);
  u16* wqkvF = (u16*)(ws + WQKVT_OFF);
  u16* pwF = (u16*)(ws + PWT_OFF);
  float* qkvb = (float*)(ws + QKVB_OFF);
  float* bias16F = (float*)(ws + BIAS_OFF);
  float* scalef = (float*)(ws + SCALE_OFF);
  float* pbf = (float*)(ws + PB_OFF);

  if (b < 128) {
    // qkv_w row b (input-dim b): out-col c -> fragment addr.
    // W^T[c][b] lands at ((sub*6+nt)*4+ks)*512 + (lq*16+l16)*8 + j
    //   sub=c/96 nt=(c%96)/16 l16=c%16 ; ks=b/32 lq=(b%32)/8 j=b%8
    int ks = b >> 5, lq = (b >> 3) & 3, j = b & 7;
    for (int c = t; c < 384; c += 256) {
      int sub = c / 96, rr = c % 96;
      int nt = rr >> 4, l16 = rr & 15;
      int addr = (((sub * 6 + nt) * 4 + ks) << 9) + ((lq * 16 + l16) << 3) + j;
      wqkvF[addr] = f2bf(gld(qkv_w, b * 384 + c, isbf));
    }
  } else if (b < 256) {    // proj_w row r=b-128 (input-dim)
    int r = b - 128;
    int ks = r >> 5, lq = (r >> 3) & 3, j = r & 7;
    if (t < 128) {
      int sub = t >> 5, rr = t & 31;
      int nt = rr >> 4, l16 = rr & 15;
      int addr = (((sub * 2 + nt) * 4 + ks) << 9) + ((lq * 16 + l16) << 3) + j;
      pwF[addr] = f2bf(gld(proj_w, r * 128 + t, isbf));
    }
  } else if (b == 256) {   // small vectors
    for (int o = t; o < 384; o += 256) {
      float v = 0.f;
      if (o < 128) v = gld(q_bias, o, isbf);
      else if (o >= 256) v = gld(v_bias, o - 256, isbf);
      qkvb[o] = v;
    }
    if (t < 128) pbf[t] = gld(proj_b, t, isbf);
    if (t < 4) scalef[t] = expf(fminf(gld(ls, t, isbf), 4.60517019f));
  } else {                 // CPB MLP -> 16*sigmoid, fragment-order bias16F
    __shared__ float w1[1024];   // [2][512]
    __shared__ float b1[512];
    __shared__ float w2[2048];   // [512][4]
    __shared__ float tab[225][4];
    for (int i = t; i < 1024; i += 256) w1[i] = gld(cpb_w1, i, isbf);
    for (int i = t; i < 512; i += 256) b1[i] = gld(cpb_b1, i, isbf);
    for (int i = t; i < 2048; i += 256) w2[i] = gld(cpb_w2, i, isbf);
    __syncthreads();
    if (t < 225) {
      int i = t / 15, j = t % 15;
      float c0, c1;
      {
        float tt = ((float)(i - 7) / 7.0f) * 8.0f;
        float s = (tt > 0.f) ? 1.f : ((tt < 0.f) ? -1.f : 0.f);
        c0 = s * log2f(fabsf(tt) + 1.f) / 3.0f;
      }
      {
        float tt = ((float)(j - 7) / 7.0f) * 8.0f;
        float s = (tt > 0.f) ? 1.f : ((tt < 0.f) ? -1.f : 0.f);
        c1 = s * log2f(fabsf(tt) + 1.f) / 3.0f;
      }
      float acc[4] = {0.f, 0.f, 0.f, 0.f};
      for (int jj = 0; jj < 512; jj++) {
        float h = fmaxf(c0 * w1[jj] + c1 * w1[512 + jj] + b1[jj], 0.f);
        #pragma unroll
        for (int hh = 0; hh < 4; hh++) acc[hh] += h * w2[jj * 4 + hh];
      }
      #pragma unroll
      for (int hh = 0; hh < 4; hh++) tab[t][hh] = acc[hh];
    }
    __syncthreads();
    // bias16F[e]: e = h*4096 + mg*2048 + qt*1024 + kt*256 + lane*4 + r
    //   q = 32mg+16qt+(lane&15), k = 16kt+4(lane>>4)+r
    for (int e = t; e < 4 * 64 * 64; e += 256) {
      int h = e >> 12, mg = (e >> 11) & 1, qt = (e >> 10) & 1;
      int kt = (e >> 8) & 3, lane = (e >> 2) & 63, r = e & 3;
      int q = 32 * mg + 16 * qt + (lane & 15);
      int kk = 16 * kt + 4 * (lane >> 4) + r;
      int dr = (q >> 3) - (kk >> 3) + 7;
      int dc = (q & 7) - (kk & 7) + 7;
      float v = tab[dr * 15 + dc][h];
      bias16F[e] = 16.f / (1.f + expf(-v));
    }
  }
}

// ---------------- fused per-window kernel (round-8) ----------------
// One block per window (B*256 blocks), 512 threads = 8 waves.
// = round-7 body with all ws-side operand loads in fragment order (coalesced,
//   base + const + lane*16B). Mask gather (input layout fixed) kept: 8 instrs.
// LDS (u16 elements, 32768 total = 64KB):
//   X [0,8192)  Q [8192,16384)  K [16384,24576)  VT [24576,32768)
//   P overlays [0,16384) (X+Q, both dead);  AO overlays [16384,24576) (K, dead)
#define X_OFF 0
#define Q_OFF 8192
#define K_OFF 16384
#define VT_OFF 24576
#define P_OFF 0
#define AO_OFF 16384

__global__ __launch_bounds__(512, 4) void swin_main(
    const void* __restrict__ x, const void* __restrict__ mask,
    const char* __restrict__ ws, void* __restrict__ out) {
  __shared__ __align__(16) u16 lds[32768];
  const f32x4 fz = {0.f, 0.f, 0.f, 0.f};

  const u16* wqkvF = (const u16*)(ws + WQKVT_OFF);
  const u16* pwF = (const u16*)(ws + PWT_OFF);
  const float* qkvb = (const float*)(ws + QKVB_OFF);
  const float* bias16F = (const float*)(ws + BIAS_OFF);
  const float* scalef = (const float*)(ws + SCALE_OFF);
  const float* pbf = (const float*)(ws + PB_OFF);
  const int isbf = (int)*(const unsigned int*)(ws + FLAG_OFF);

  const int tid = threadIdx.x;
  const int wid = tid >> 6;
  const int lane = tid & 63;
  const int ln16 = lane & 15;
  const int lq = lane >> 4;
  const int q8 = lq << 3;
  const int mg = wid >> 2;   // row half: 0/1
  const int sub = wid & 3;   // col slice / head

  const int wi = blockIdx.x;
  const int b = wi >> 8;
  const int rem = wi & 255;
  const int wy = rem >> 4, wx = rem & 15;
  const int xbase = ((b * 128 + wy * 8) * 128 + wx * 8) * 128;

  // ---- stage 1: X tile -> LDS as bf16 (coalesced) ----
  if (isbf) {
    const u16* xb = (const u16*)x;
    #pragma unroll
    for (int rep = 0; rep < 2; rep++) {
      int ch = tid + rep * 512;          // 1024 chunks of 8 elements
      int token = ch >> 4, dch = ch & 15;
      int r = token >> 3, c = token & 7;
      i32x4 v = *(const i32x4_a*)(xb + xbase + r * 16384 + c * 128 + dch * 8);
      *(i32x4_a*)(lds + X_OFF + sw(token, dch * 8, 128)) = v;
    }
  } else {
    const float* xf = (const float*)x;
    #pragma unroll
    for (int rep = 0; rep < 2; rep++) {
      int ch = tid + rep * 512;
      int token = ch >> 4, dch = ch & 15;
      int r = token >> 3, c = token & 7;
      const float* src = xf + xbase + r * 16384 + c * 128 + dch * 8;
      union { i32x4 v2[2]; float f[8]; } in;
      in.v2[0] = *(const i32x4_a*)(src);
      in.v2[1] = *(const i32x4_a*)(src + 4);
      union { u16 u[8]; i32x4 v; } o;
      #pragma unroll
      for (int d = 0; d < 8; d++) o.u[d] = f2bf(in.f[d]);
      *(i32x4_a*)(lds + X_OFF + sw(token, dch * 8, 128)) = o.v;
    }
  }
  __syncthreads();  // B0: X visible

  // ---- stage 2: GEMM1  qkv = X @ Wqkv + b  (bias folded into C init) ----
  f32x4 acc1[2][6];
  #pragma unroll
  for (int nt = 0; nt < 6; nt++) {
    float bv = qkvb[96 * sub + 16 * nt + ln16];
    f32x4 ci = {bv, bv, bv, bv};
    acc1[0][nt] = ci;
    acc1[1][nt] = ci;
  }

  #pragma unroll
  for (int ks = 0; ks < 4; ks++) {
    bf16x8 a0 = *(const bf16x8_a*)(lds + X_OFF + sw(32 * mg + ln16, 32 * ks + q8, 128));
    bf16x8 a1 = *(const bf16x8_a*)(lds + X_OFF + sw(32 * mg + 16 + ln16, 32 * ks + q8, 128));
    bf16x8 bb[6];
    #pragma unroll
    for (int nt = 0; nt < 6; nt++)
      bb[nt] = *(const bf16x8_a*)(wqkvF + (((sub * 6 + nt) * 4 + ks) << 9) + lane * 8);
    #pragma unroll
    for (int nt = 0; nt < 6; nt++) {
      acc1[0][nt] = __builtin_amdgcn_mfma_f32_16x16x32_bf16(a0, bb[nt], acc1[0][nt], 0, 0, 0);
      acc1[1][nt] = __builtin_amdgcn_mfma_f32_16x16x32_bf16(a1, bb[nt], acc1[1][nt], 0, 0, 0);
    }
  }

  // epilogue: per 32-col chunk -> q/k normalized rows (q pre-scaled) written
  // to their own disjoint LDS regions immediately; v transposed + packed.
  #pragma unroll
  for (int ci = 0; ci < 3; ci++) {
    int n0 = 96 * sub + 32 * ci;
    int type = n0 >> 7;              // 0=q 1=k 2=v
    int head = (n0 & 127) >> 5;
    int nt0 = 2 * ci, nt1 = nt0 + 1;
    if (type < 2) {
      int base = (type == 0) ? Q_OFF : K_OFF;
      float sh = (type == 0) ? scalef[head] : 1.0f;  // fold logit scale into q
      #pragma unroll
      for (int mt = 0; mt < 2; mt++)
        #pragma unroll
        for (int r = 0; r < 4; r++) {
          float x0 = acc1[mt][nt0][r], x1 = acc1[mt][nt1][r];
          float ss = x0 * x0 + x1 * x1;
          ss += __shfl_xor(ss, 1);
          ss += __shfl_xor(ss, 2);
          ss += __shfl_xor(ss, 4);
          ss += __shfl_xor(ss, 8);
          float inv = sh / fmaxf(sqrtf(ss), 1e-12f);
          int row = 32 * mg + 16 * mt + 4 * lq + r;
          lds[base + sw(row, head * 32 + ln16, 128)] = f2bf(x0 * inv);
          lds[base + sw(row, head * 32 + 16 + ln16, 128)] = f2bf(x1 * inv);
        }
    } else {
      // v: transposed, packed — 4 consecutive cols (tokens) per lane -> i32x2
      #pragma unroll
      for (int mt = 0; mt < 2; mt++) {
        int c0 = 32 * mg + 16 * mt + 4 * lq;
        unsigned int w0 = (unsigned int)f2bf(acc1[mt][nt0][0]) | ((unsigned int)f2bf(acc1[mt][nt0][1]) << 16);
        unsigned int w1 = (unsigned int)f2bf(acc1[mt][nt0][2]) | ((unsigned int)f2bf(acc1[mt][nt0][3]) << 16);
        i32x2 wv = {(int)w0, (int)w1};
        *(i32x2_a*)(lds + VT_OFF + sw(head * 32 + ln16, c0, 64)) = wv;
        unsigned int u0 = (unsigned int)f2bf(acc1[mt][nt1][0]) | ((unsigned int)f2bf(acc1[mt][nt1][1]) << 16);
        unsigned int u1 = (unsigned int)f2bf(acc1[mt][nt1][2]) | ((unsigned int)f2bf(acc1[mt][nt1][3]) << 16);
        i32x2 uv = {(int)u0, (int)u1};
        *(i32x2_a*)(lds + VT_OFF + sw(head * 32 + 16 + ln16, c0, 64)) = uv;
      }
    }
  }
  __syncthreads();  // B1: Q/K/VT visible (and all X reads done)

  // ---- stage 3: S^T = k.(q*scale)^T + (bias+mask)^T (as MFMA C), softmax ----
  // Swapped operands: A = K rows, B = Q rows -> C layout has q = lane&15 (col),
  // k = 4*lq + r (row). Softmax over k = in-reg reduce + xor16 + xor32.
  const int h = sub;
  bf16x8 kf[4], qf[2];
  #pragma unroll
  for (int kt = 0; kt < 4; kt++)
    kf[kt] = *(const bf16x8_a*)(lds + K_OFF + sw(16 * kt + ln16, h * 32 + q8, 128));
  #pragma unroll
  for (int qt = 0; qt < 2; qt++)
    qf[qt] = *(const bf16x8_a*)(lds + Q_OFF + sw(32 * mg + 16 * qt + ln16, h * 32 + q8, 128));

  // C-init: bias from fragment-order table (coalesced f32x4), mask gather kept
  const u16* mk16 = (const u16*)mask;
  const float* mkf = (const float*)mask;
  f32x4 ST[4][2];
  #pragma unroll
  for (int qt = 0; qt < 2; qt++) {
    int q = 32 * mg + 16 * qt + ln16;
    #pragma unroll
    for (int kt = 0; kt < 4; kt++) {
      f32x4 bv = *(const f32x4_a*)(bias16F + h * 4096 + mg * 2048 + qt * 1024 + kt * 256 + lane * 4);
      int bi = q * 64 + 16 * kt + 4 * lq;
      f32x4 cv;
      if (isbf) {
        u64_a mw = *(const u64_a*)(mk16 + rem * 4096 + bi);
        cv[0] = bv[0] + bf2f((u16)mw);
        cv[1] = bv[1] + bf2f((u16)(mw >> 16));
        cv[2] = bv[2] + bf2f((u16)(mw >> 32));
        cv[3] = bv[3] + bf2f((u16)(mw >> 48));
      } else {
        f32x4 mv = *(const f32x4_a*)(mkf + rem * 4096 + bi);
        cv = bv + mv;
      }
      ST[kt][qt] = cv;
    }
  }
  #pragma unroll
  for (int kt = 0; kt < 4; kt++)
    #pragma unroll
    for (int qt = 0; qt < 2; qt++)
      ST[kt][qt] = __builtin_amdgcn_mfma_f32_16x16x32_bf16(kf[kt], qf[qt], ST[kt][qt], 0, 0, 0);

  // softmax over k (rows of S^T): per q-column, 16 in-reg values + 2 shuffles
  #pragma unroll
  for (int qt = 0; qt < 2; qt++) {
    float m = ST[0][qt][0];
    #pragma unroll
    for (int kt = 0; kt < 4; kt++)
      #pragma unroll
      for (int r = 0; r < 4; r++) m = fmaxf(m, ST[kt][qt][r]);
    m = fmaxf(m, __shfl_xor(m, 16));
    m = fmaxf(m, __shfl_xor(m, 32));
    float sum = 0.f;
    #pragma unroll
    for (int kt = 0; kt < 4; kt++)
      #pragma unroll
      for (int r = 0; r < 4; r++) {
        float p = __expf(ST[kt][qt][r] - m);
        ST[kt][qt][r] = p;
        sum += p;
      }
    sum += __shfl_xor(sum, 16);
    sum += __shfl_xor(sum, 32);
    float inv = 1.0f / sum;
    #pragma unroll
    for (int kt = 0; kt < 4; kt++)
      #pragma unroll
      for (int r = 0; r < 4; r++) ST[kt][qt][r] *= inv;
  }
  __syncthreads();  // B2: all Q/K reads done before P overlays X+Q

  // ---- stage 4/5: P -> LDS (8x 8B stores), O = P @ V ----
  #pragma unroll
  for (int qt = 0; qt < 2; qt++)
    #pragma unroll
    for (int kt = 0; kt < 4; kt++) {
      int row = 32 * mg + 16 * qt + ln16;
      int col = h * 64 + 16 * kt + 4 * lq;
      unsigned int w0 = (unsigned int)f2bf(ST[kt][qt][0]) | ((unsigned int)f2bf(ST[kt][qt][1]) << 16);
      unsigned int w1 = (unsigned int)f2bf(ST[kt][qt][2]) | ((unsigned int)f2bf(ST[kt][qt][3]) << 16);
      i32x2 wv = {(int)w0, (int)w1};
      *(i32x2_a*)(lds + P_OFF + sw(row, col, 256)) = wv;
    }
  __syncthreads();  // B3: P visible
  f32x4 O[2][2];
  O[0][0] = fz; O[0][1] = fz; O[1][0] = fz; O[1][1] = fz;
  #pragma unroll
  for (int ks = 0; ks < 2; ks++) {
    bf16x8 pf[2], vf[2];
    #pragma unroll
    for (int mt = 0; mt < 2; mt++)
      pf[mt] = *(const bf16x8_a*)(lds + P_OFF + sw(32 * mg + 16 * mt + ln16, h * 64 + 32 * ks + q8, 256));
    #pragma unroll
    for (int nt = 0; nt < 2; nt++)
      vf[nt] = *(const bf16x8_a*)(lds + VT_OFF + sw(h * 32 + 16 * nt + ln16, 32 * ks + q8, 64));
    #pragma unroll
    for (int mt = 0; mt < 2; mt++)
      #pragma unroll
      for (int nt = 0; nt < 2; nt++)
        O[mt][nt] = __builtin_amdgcn_mfma_f32_16x16x32_bf16(pf[mt], vf[nt], O[mt][nt], 0, 0, 0);
  }
  // AO region (old K) is disjoint from P and VT -> store immediately, no barrier
  #pragma unroll
  for (int mt = 0; mt < 2; mt++)
    #pragma unroll
    for (int nt = 0; nt < 2; nt++)
      #pragma unroll
      for (int r = 0; r < 4; r++) {
        int row = 32 * mg + 16 * mt + 4 * lq + r;
        lds[AO_OFF + sw(row, h * 32 + 16 * nt + ln16, 128)] = f2bf(O[mt][nt][r]);
      }
  __syncthreads();  // B4: AO visible

  // ---- stage 6: out = AO @ proj_w + proj_b (bias folded into C init) ----
  float pb0 = pbf[32 * sub + ln16];
  float pb1 = pbf[32 * sub + 16 + ln16];
  f32x4 acc3[2][2];
  {
    f32x4 c0 = {pb0, pb0, pb0, pb0};
    f32x4 c1 = {pb1, pb1, pb1, pb1};
    acc3[0][0] = c0; acc3[0][1] = c1; acc3[1][0] = c0; acc3[1][1] = c1;
  }
  #pragma unroll
  for (int ks = 0; ks < 4; ks++) {
    bf16x8 a0 = *(const bf16x8_a*)(lds + AO_OFF + sw(32 * mg + ln16, 32 * ks + q8, 128));
    bf16x8 a1 = *(const bf16x8_a*)(lds + AO_OFF + sw(32 * mg + 16 + ln16, 32 * ks + q8, 128));
    bf16x8 b0 = *(const bf16x8_a*)(pwF + (((sub * 2 + 0) * 4 + ks) << 9) + lane * 8);
    bf16x8 b1 = *(const bf16x8_a*)(pwF + (((sub * 2 + 1) * 4 + ks) << 9) + lane * 8);
    acc3[0][0] = __builtin_amdgcn_mfma_f32_16x16x32_bf16(a0, b0, acc3[0][0], 0, 0, 0);
    acc3[0][1] = __builtin_amdgcn_mfma_f32_16x16x32_bf16(a0, b1, acc3[0][1], 0, 0, 0);
    acc3[1][0] = __builtin_amdgcn_mfma_f32_16x16x32_bf16(a1, b0, acc3[1][0], 0, 0, 0);
    acc3[1][1] = __builtin_amdgcn_mfma_f32_16x16x32_bf16(a1, b1, acc3[1][1], 0, 0, 0);
  }
  if (isbf) {
    u16* ob = (u16*)out;
    #pragma unroll
    for (int mt = 0; mt < 2; mt++)
      #pragma unroll
      for (int r = 0; r < 4; r++) {
        int row = 32 * mg + 16 * mt + 4 * lq + r;
        int o = xbase + (row >> 3) * 16384 + (row & 7) * 128 + 32 * sub;
        ob[o + ln16] = f2bf(acc3[mt][0][r]);
        ob[o + 16 + ln16] = f2bf(acc3[mt][1][r]);
      }
  } else {
    float* of = (float*)out;
    #pragma unroll
    for (int mt = 0; mt < 2; mt++)
      #pragma unroll
      for (int r = 0; r < 4; r++) {
        int row = 32 * mg + 16 * mt + 4 * lq + r;
        int o = xbase + (row >> 3) * 16384 + (row & 7) * 128 + 32 * sub;
        of[o + ln16] = acc3[mt][0][r];
        of[o + 16 + ln16] = acc3[mt][1][r];
      }
  }
}

extern "C" void kernel_launch(void* const* d_in, const int* in_sizes, int n_in,
                              void* d_out, int out_size, void* d_ws, size_t ws_size,
                              hipStream_t stream) {
  const void* x      = d_in[0];
  const void* mask   = d_in[1];
  const void* qkv_w  = d_in[2];
  const void* q_bias = d_in[3];
  const void* v_bias = d_in[4];
  const void* ls     = d_in[5];
  const void* cpb_w1 = d_in[6];
  const void* cpb_b1 = d_in[7];
  const void* cpb_w2 = d_in[8];
  const void* proj_w = d_in[9];
  const void* proj_b = d_in[10];
  const int B = in_sizes[0] / (128 * 128 * 128);

  char* ws = (char*)d_ws;
  swin_detect<<<1, 64, 0, stream>>>((const unsigned int*)x,
                                    (unsigned int*)(ws + FLAG_OFF));
  swin_setup<<<258, 256, 0, stream>>>(qkv_w, q_bias, v_bias, ls, cpb_w1, cpb_b1,
                                      cpb_w2, proj_w, proj_b, ws);
  swin_main<<<B * 256, 512, 0, stream>>>(x, mask, ws, d_out);
}

// Round 8
// 363.510 us; speedup vs baseline: 1.3762x; 1.0261x over previous
//
#include <hip/hip_runtime.h>

typedef unsigned short u16;
typedef __bf16 bf16x8 __attribute__((ext_vector_type(8)));
typedef float f32x4 __attribute__((ext_vector_type(4)));
typedef int i32x4 __attribute__((ext_vector_type(4)));
typedef int i32x2 __attribute__((ext_vector_type(2)));
// may_alias: LDS/global buffers are accessed as u16, i32x2/4, f32x4 and bf16x8 —
// without this, TBAA lets the compiler reorder the P-matrix stores vs loads.
typedef i32x4 i32x4_a __attribute__((may_alias));
typedef i32x2 i32x2_a __attribute__((may_alias));
typedef bf16x8 bf16x8_a __attribute__((may_alias));
typedef f32x4 f32x4_a __attribute__((may_alias));
typedef unsigned long long u64_a __attribute__((may_alias));

__device__ __forceinline__ float bf2f(u16 u) {
  union { unsigned int i; float f; } c;
  c.i = ((unsigned int)u) << 16;
  return c.f;
}
// Native cast -> v_cvt_pk_bf16_f32 (RNE).
__device__ __forceinline__ u16 f2bf(float f) {
  union { __bf16 h; u16 u; } c;
  c.h = (__bf16)f;
  return c.u;
}
// dual-dtype scalar load: isbf ? bf16[i] : f32[i]
__device__ __forceinline__ float gld(const void* p, int i, int isbf) {
  return isbf ? bf2f(((const u16*)p)[i]) : ((const float*)p)[i];
}
// XOR-swizzled LDS element offset (16B blocks swizzled by row low 3 bits).
__device__ __forceinline__ int sw(int row, int col, int rs) {
  return row * rs + ((((col >> 3) ^ (row & 7)) << 3) | (col & 7));
}

// ws layout (bytes):  [fragment-order operand layouts]
//   0      : wqkvF  bf16 [4sub][6nt][4ks][64lane][8]  (98304)
//   98304  : pwF    bf16 [4sub][2nt][4ks][64lane][8]  (32768)
//   131072 : qkvb   f32  [384]        (1536)
//   132608 : bias16F f32 [4h][2mg][2qt][4kt][64lane][4r] (65536)
//   198144 : scalef f32  [4]          (16)     == exp(min(logit_scale, ln100))
//   198160 : pbf    f32  [128]        (512)
//   198672 : flag   u32  (1=bf16 inputs, 0=f32 inputs)
//   200704 : maskF  f32  [256w][2mg][2qt][4kt][64lane][4r]  (4MB, OPTIONAL —
//            only if ws_size permits; kills the last row-gather)
#define WQKVT_OFF 0
#define PWT_OFF   98304
#define QKVB_OFF  131072
#define BIAS_OFF  132608
#define SCALE_OFF 198144
#define PB_OFF    198160
#define FLAG_OFF  198672
#define MASKF_OFF 200704
#define MASKF_NEED (200704ull + 4ull * 1024 * 1024)

// ---------------- dtype probe ----------------
__global__ void swin_detect(const unsigned int* __restrict__ xw,
                            unsigned int* __restrict__ flag) {
  int t = threadIdx.x;  // 64 threads
  int cnt = 0;
  for (int i = 0; i < 8; i++) {
    unsigned int w = xw[t * 8 + i];
    unsigned int lo = w & 0xffffu;
    unsigned int e = (lo >> 7) & 0xffu;
    if ((e >= 0x70u && e <= 0x82u) || lo == 0u) cnt++;
  }
  cnt += __shfl_xor(cnt, 1);
  cnt += __shfl_xor(cnt, 2);
  cnt += __shfl_xor(cnt, 4);
  cnt += __shfl_xor(cnt, 8);
  cnt += __shfl_xor(cnt, 16);
  cnt += __shfl_xor(cnt, 32);
  if (t == 0) *flag = (cnt >= 256) ? 1u : 0u;
}

// ---------------- setup v3: fragment-order weight layouts ----------------
__global__ void swin_setup(const void* __restrict__ qkv_w, const void* __restrict__ q_bias,
                           const void* __restrict__ v_bias, const void* __restrict__ ls,
                           const void* __restrict__ cpb_w1, const void* __restrict__ cpb_b1,
                           const void* __restrict__ cpb_w2, const void* __restrict__ proj_w,
                           const void* __restrict__ proj_b, char* __restrict__ ws) {
  const int b = blockIdx.x, t = threadIdx.x;
  const int isbf = (int)*(const unsigned int*)(ws + FLAG_OFF);
  u16* wqkvF = (u16*)(ws + WQKVT_OFF);
  u16* pwF = (u16*)(ws + PWT_OFF);
  float* qkvb = (float*)(ws + QKVB_OFF);
  float* bias16F = (float*)(ws + BIAS_OFF);
  float* scalef = (float*)(ws + SCALE_OFF);
  float* pbf = (float*)(ws + PB_OFF);

  if (b < 128) {
    // qkv_w row b (input-dim b): out-col c -> fragment addr.
    int ks = b >> 5, lq = (b >> 3) & 3, j = b & 7;
    for (int c = t; c < 384; c += 256) {
      int sub = c / 96, rr = c % 96;
      int nt = rr >> 4, l16 = rr & 15;
      int addr = (((sub * 6 + nt) * 4 + ks) << 9) + ((lq * 16 + l16) << 3) + j;
      wqkvF[addr] = f2bf(gld(qkv_w, b * 384 + c, isbf));
    }
  } else if (b < 256) {    // proj_w row r=b-128 (input-dim)
    int r = b - 128;
    int ks = r >> 5, lq = (r >> 3) & 3, j = r & 7;
    if (t < 128) {
      int sub = t >> 5, rr = t & 31;
      int nt = rr >> 4, l16 = rr & 15;
      int addr = (((sub * 2 + nt) * 4 + ks) << 9) + ((lq * 16 + l16) << 3) + j;
      pwF[addr] = f2bf(gld(proj_w, r * 128 + t, isbf));
    }
  } else if (b == 256) {   // small vectors
    for (int o = t; o < 384; o += 256) {
      float v = 0.f;
      if (o < 128) v = gld(q_bias, o, isbf);
      else if (o >= 256) v = gld(v_bias, o - 256, isbf);
      qkvb[o] = v;
    }
    if (t < 128) pbf[t] = gld(proj_b, t, isbf);
    if (t < 4) scalef[t] = expf(fminf(gld(ls, t, isbf), 4.60517019f));
  } else {                 // CPB MLP -> 16*sigmoid, fragment-order bias16F
    __shared__ float w1[1024];   // [2][512]
    __shared__ float b1[512];
    __shared__ float w2[2048];   // [512][4]
    __shared__ float tab[225][4];
    for (int i = t; i < 1024; i += 256) w1[i] = gld(cpb_w1, i, isbf);
    for (int i = t; i < 512; i += 256) b1[i] = gld(cpb_b1, i, isbf);
    for (int i = t; i < 2048; i += 256) w2[i] = gld(cpb_w2, i, isbf);
    __syncthreads();
    if (t < 225) {
      int i = t / 15, j = t % 15;
      float c0, c1;
      {
        float tt = ((float)(i - 7) / 7.0f) * 8.0f;
        float s = (tt > 0.f) ? 1.f : ((tt < 0.f) ? -1.f : 0.f);
        c0 = s * log2f(fabsf(tt) + 1.f) / 3.0f;
      }
      {
        float tt = ((float)(j - 7) / 7.0f) * 8.0f;
        float s = (tt > 0.f) ? 1.f : ((tt < 0.f) ? -1.f : 0.f);
        c1 = s * log2f(fabsf(tt) + 1.f) / 3.0f;
      }
      float acc[4] = {0.f, 0.f, 0.f, 0.f};
      for (int jj = 0; jj < 512; jj++) {
        float h = fmaxf(c0 * w1[jj] + c1 * w1[512 + jj] + b1[jj], 0.f);
        #pragma unroll
        for (int hh = 0; hh < 4; hh++) acc[hh] += h * w2[jj * 4 + hh];
      }
      #pragma unroll
      for (int hh = 0; hh < 4; hh++) tab[t][hh] = acc[hh];
    }
    __syncthreads();
    // bias16F[e]: e = h*4096 + mg*2048 + qt*1024 + kt*256 + lane*4 + r
    //   q = 32mg+16qt+(lane&15), k = 16kt+4(lane>>4)+r
    for (int e = t; e < 4 * 64 * 64; e += 256) {
      int h = e >> 12, mg = (e >> 11) & 1, qt = (e >> 10) & 1;
      int kt = (e >> 8) & 3, lane = (e >> 2) & 63, r = e & 3;
      int q = 32 * mg + 16 * qt + (lane & 15);
      int kk = 16 * kt + 4 * (lane >> 4) + r;
      int dr = (q >> 3) - (kk >> 3) + 7;
      int dc = (q & 7) - (kk & 7) + 7;
      float v = tab[dr * 15 + dc][h];
      bias16F[e] = 16.f / (1.f + expf(-v));
    }
  }
}

// ---------------- setup: fragment-order mask (optional) ----------
// mask[w][q][k] -> maskF[w][mg][qt][kt][lane][r]. Coalesced read, scattered
// (fire-and-forget) write, one block per window. Removes swin_main's last
// 256B-stride row gather (8 instrs/wave, ~16 cache lines each).
__global__ void swin_setup_mask(const void* __restrict__ mask, char* __restrict__ ws) {
  const int w = blockIdx.x, t = threadIdx.x;
  const int isbf = (int)*(const unsigned int*)(ws + FLAG_OFF);
  float* maskF = (float*)(ws + MASKF_OFF);
  #pragma unroll
  for (int i = 0; i < 16; i++) {
    int e = t + i * 256;               // 4096 elems per window
    int q = e >> 6, k = e & 63;
    int mg = q >> 5, qt = (q >> 4) & 1, l16 = q & 15;
    int kt = k >> 4, lq = (k >> 2) & 3, r = k & 3;
    int addr = w * 4096 + ((mg * 2 + qt) * 4 + kt) * 256 + ((lq * 16 + l16) << 2) + r;
    maskF[addr] = gld(mask, w * 4096 + e, isbf);
  }
}

// ---------------- fused per-window kernel (round-9, resubmit) --------------
// One block per window (B*256 blocks), 512 threads = 8 waves.
// Round-10 note: round-9 bench never ran (container acquire failed twice —
// infra, not kernel: no compile error / no failed correctness). Re-audited the
// two risky edits (B3 removal: P slice is strictly intra-wave incl. swizzle,
// LDS in-order per wave; maskF: host-gated on ws_size) — resubmitting as-is.
// Changes vs round-8 (205us):
//  1. MF=1: mask C-init from fragment-order maskF (f32x4 coalesced) instead of
//     the 256B-stride u64 gather. MF=0 fallback keeps gather (small ws).
//  2. C-init issued BEFORE the kf/qf ds_reads: VMEM latency overlaps LDS reads.
//  3. B3 removed: P never crosses waves (wave (mg,h) writes rows 32mg+16qt+ln16
//     x cols [64h,64h+64) and reads the same slice; swizzle permutes only
//     within the 64-col slice); intra-wave LDS write->read is in-order.
//     Barriers 5 -> 4. (B2 stays: cross-wave WAR on Q/K before P overlays.)
// LDS (u16 elements, 32768 total = 64KB):
//   X [0,8192)  Q [8192,16384)  K [16384,24576)  VT [24576,32768)
//   P overlays [0,16384) (X+Q, both dead);  AO overlays [16384,24576) (K, dead)
#define X_OFF 0
#define Q_OFF 8192
#define K_OFF 16384
#define VT_OFF 24576
#define P_OFF 0
#define AO_OFF 16384

template <int MF>
__global__ __launch_bounds__(512, 4) void swin_main(
    const void* __restrict__ x, const void* __restrict__ mask,
    const char* __restrict__ ws, void* __restrict__ out) {
  __shared__ __align__(16) u16 lds[32768];
  const f32x4 fz = {0.f, 0.f, 0.f, 0.f};

  const u16* wqkvF = (const u16*)(ws + WQKVT_OFF);
  const u16* pwF = (const u16*)(ws + PWT_OFF);
  const float* qkvb = (const float*)(ws + QKVB_OFF);
  const float* bias16F = (const float*)(ws + BIAS_OFF);
  const float* scalef = (const float*)(ws + SCALE_OFF);
  const float* pbf = (const float*)(ws + PB_OFF);
  const int isbf = (int)*(const unsigned int*)(ws + FLAG_OFF);

  const int tid = threadIdx.x;
  const int wid = tid >> 6;
  const int lane = tid & 63;
  const int ln16 = lane & 15;
  const int lq = lane >> 4;
  const int q8 = lq << 3;
  const int mg = wid >> 2;   // row half: 0/1
  const int sub = wid & 3;   // col slice / head

  const int wi = blockIdx.x;
  const int b = wi >> 8;
  const int rem = wi & 255;
  const int wy = rem >> 4, wx = rem & 15;
  const int xbase = ((b * 128 + wy * 8) * 128 + wx * 8) * 128;

  // ---- stage 1: X tile -> LDS as bf16 (coalesced) ----
  if (isbf) {
    const u16* xb = (const u16*)x;
    #pragma unroll
    for (int rep = 0; rep < 2; rep++) {
      int ch = tid + rep * 512;          // 1024 chunks of 8 elements
      int token = ch >> 4, dch = ch & 15;
      int r = token >> 3, c = token & 7;
      i32x4 v = *(const i32x4_a*)(xb + xbase + r * 16384 + c * 128 + dch * 8);
      *(i32x4_a*)(lds + X_OFF + sw(token, dch * 8, 128)) = v;
    }
  } else {
    const float* xf = (const float*)x;
    #pragma unroll
    for (int rep = 0; rep < 2; rep++) {
      int ch = tid + rep * 512;
      int token = ch >> 4, dch = ch & 15;
      int r = token >> 3, c = token & 7;
      const float* src = xf + xbase + r * 16384 + c * 128 + dch * 8;
      union { i32x4 v2[2]; float f[8]; } in;
      in.v2[0] = *(const i32x4_a*)(src);
      in.v2[1] = *(const i32x4_a*)(src + 4);
      union { u16 u[8]; i32x4 v; } o;
      #pragma unroll
      for (int d = 0; d < 8; d++) o.u[d] = f2bf(in.f[d]);
      *(i32x4_a*)(lds + X_OFF + sw(token, dch * 8, 128)) = o.v;
    }
  }
  __syncthreads();  // B0: X visible

  // ---- stage 2: GEMM1  qkv = X @ Wqkv + b  (bias folded into C init) ----
  f32x4 acc1[2][6];
  #pragma unroll
  for (int nt = 0; nt < 6; nt++) {
    float bv = qkvb[96 * sub + 16 * nt + ln16];
    f32x4 ci = {bv, bv, bv, bv};
    acc1[0][nt] = ci;
    acc1[1][nt] = ci;
  }

  #pragma unroll
  for (int ks = 0; ks < 4; ks++) {
    bf16x8 a0 = *(const bf16x8_a*)(lds + X_OFF + sw(32 * mg + ln16, 32 * ks + q8, 128));
    bf16x8 a1 = *(const bf16x8_a*)(lds + X_OFF + sw(32 * mg + 16 + ln16, 32 * ks + q8, 128));
    bf16x8 bb[6];
    #pragma unroll
    for (int nt = 0; nt < 6; nt++)
      bb[nt] = *(const bf16x8_a*)(wqkvF + (((sub * 6 + nt) * 4 + ks) << 9) + lane * 8);
    #pragma unroll
    for (int nt = 0; nt < 6; nt++) {
      acc1[0][nt] = __builtin_amdgcn_mfma_f32_16x16x32_bf16(a0, bb[nt], acc1[0][nt], 0, 0, 0);
      acc1[1][nt] = __builtin_amdgcn_mfma_f32_16x16x32_bf16(a1, bb[nt], acc1[1][nt], 0, 0, 0);
    }
  }

  // epilogue: per 32-col chunk -> q/k normalized rows (q pre-scaled) written
  // to their own disjoint LDS regions immediately; v transposed + packed.
  #pragma unroll
  for (int ci = 0; ci < 3; ci++) {
    int n0 = 96 * sub + 32 * ci;
    int type = n0 >> 7;              // 0=q 1=k 2=v
    int head = (n0 & 127) >> 5;
    int nt0 = 2 * ci, nt1 = nt0 + 1;
    if (type < 2) {
      int base = (type == 0) ? Q_OFF : K_OFF;
      float sh = (type == 0) ? scalef[head] : 1.0f;  // fold logit scale into q
      #pragma unroll
      for (int mt = 0; mt < 2; mt++)
        #pragma unroll
        for (int r = 0; r < 4; r++) {
          float x0 = acc1[mt][nt0][r], x1 = acc1[mt][nt1][r];
          float ss = x0 * x0 + x1 * x1;
          ss += __shfl_xor(ss, 1);
          ss += __shfl_xor(ss, 2);
          ss += __shfl_xor(ss, 4);
          ss += __shfl_xor(ss, 8);
          float inv = sh / fmaxf(sqrtf(ss), 1e-12f);
          int row = 32 * mg + 16 * mt + 4 * lq + r;
          lds[base + sw(row, head * 32 + ln16, 128)] = f2bf(x0 * inv);
          lds[base + sw(row, head * 32 + 16 + ln16, 128)] = f2bf(x1 * inv);
        }
    } else {
      // v: transposed, packed — 4 consecutive cols (tokens) per lane -> i32x2
      #pragma unroll
      for (int mt = 0; mt < 2; mt++) {
        int c0 = 32 * mg + 16 * mt + 4 * lq;
        unsigned int w0 = (unsigned int)f2bf(acc1[mt][nt0][0]) | ((unsigned int)f2bf(acc1[mt][nt0][1]) << 16);
        unsigned int w1 = (unsigned int)f2bf(acc1[mt][nt0][2]) | ((unsigned int)f2bf(acc1[mt][nt0][3]) << 16);
        i32x2 wv = {(int)w0, (int)w1};
        *(i32x2_a*)(lds + VT_OFF + sw(head * 32 + ln16, c0, 64)) = wv;
        unsigned int u0 = (unsigned int)f2bf(acc1[mt][nt1][0]) | ((unsigned int)f2bf(acc1[mt][nt1][1]) << 16);
        unsigned int u1 = (unsigned int)f2bf(acc1[mt][nt1][2]) | ((unsigned int)f2bf(acc1[mt][nt1][3]) << 16);
        i32x2 uv = {(int)u0, (int)u1};
        *(i32x2_a*)(lds + VT_OFF + sw(head * 32 + 16 + ln16, c0, 64)) = uv;
      }
    }
  }
  __syncthreads();  // B1: Q/K/VT visible (and all X reads done)

  // ---- stage 3: S^T = k.(q*scale)^T + (bias+mask)^T (as MFMA C), softmax ----
  // C-init FIRST (VMEM issues early, overlaps the ds_reads below).
  const int h = sub;
  f32x4 ST[4][2];
  if (MF) {
    const float* mrow = (const float*)(ws + MASKF_OFF) + rem * 4096;
    #pragma unroll
    for (int qt = 0; qt < 2; qt++)
      #pragma unroll
      for (int kt = 0; kt < 4; kt++) {
        int fo = mg * 2048 + qt * 1024 + kt * 256 + lane * 4;
        f32x4 bv = *(const f32x4_a*)(bias16F + h * 4096 + fo);
        f32x4 mv = *(const f32x4_a*)(mrow + fo);
        ST[kt][qt] = bv + mv;
      }
  } else {
    const u16* mk16 = (const u16*)mask;
    const float* mkf = (const float*)mask;
    #pragma unroll
    for (int qt = 0; qt < 2; qt++) {
      int q = 32 * mg + 16 * qt + ln16;
      #pragma unroll
      for (int kt = 0; kt < 4; kt++) {
        f32x4 bv = *(const f32x4_a*)(bias16F + h * 4096 + mg * 2048 + qt * 1024 + kt * 256 + lane * 4);
        int bi = q * 64 + 16 * kt + 4 * lq;
        f32x4 cv;
        if (isbf) {
          u64_a mw = *(const u64_a*)(mk16 + rem * 4096 + bi);
          cv[0] = bv[0] + bf2f((u16)mw);
          cv[1] = bv[1] + bf2f((u16)(mw >> 16));
          cv[2] = bv[2] + bf2f((u16)(mw >> 32));
          cv[3] = bv[3] + bf2f((u16)(mw >> 48));
        } else {
          f32x4 mv = *(const f32x4_a*)(mkf + rem * 4096 + bi);
          cv = bv + mv;
        }
        ST[kt][qt] = cv;
      }
    }
  }

  // Swapped operands: A = K rows, B = Q rows -> C layout has q = lane&15 (col),
  // k = 4*lq + r (row). Softmax over k = in-reg reduce + xor16 + xor32.
  bf16x8 kf[4], qf[2];
  #pragma unroll
  for (int kt = 0; kt < 4; kt++)
    kf[kt] = *(const bf16x8_a*)(lds + K_OFF + sw(16 * kt + ln16, h * 32 + q8, 128));
  #pragma unroll
  for (int qt = 0; qt < 2; qt++)
    qf[qt] = *(const bf16x8_a*)(lds + Q_OFF + sw(32 * mg + 16 * qt + ln16, h * 32 + q8, 128));

  #pragma unroll
  for (int kt = 0; kt < 4; kt++)
    #pragma unroll
    for (int qt = 0; qt < 2; qt++)
      ST[kt][qt] = __builtin_amdgcn_mfma_f32_16x16x32_bf16(kf[kt], qf[qt], ST[kt][qt], 0, 0, 0);

  // softmax over k (rows of S^T): per q-column, 16 in-reg values + 2 shuffles
  #pragma unroll
  for (int qt = 0; qt < 2; qt++) {
    float m = ST[0][qt][0];
    #pragma unroll
    for (int kt = 0; kt < 4; kt++)
      #pragma unroll
      for (int r = 0; r < 4; r++) m = fmaxf(m, ST[kt][qt][r]);
    m = fmaxf(m, __shfl_xor(m, 16));
    m = fmaxf(m, __shfl_xor(m, 32));
    float sum = 0.f;
    #pragma unroll
    for (int kt = 0; kt < 4; kt++)
      #pragma unroll
      for (int r = 0; r < 4; r++) {
        float p = __expf(ST[kt][qt][r] - m);
        ST[kt][qt][r] = p;
        sum += p;
      }
    sum += __shfl_xor(sum, 16);
    sum += __shfl_xor(sum, 32);
    float inv = 1.0f / sum;
    #pragma unroll
    for (int kt = 0; kt < 4; kt++)
      #pragma unroll
      for (int r = 0; r < 4; r++) ST[kt][qt][r] *= inv;
  }
  __syncthreads();  // B2: all Q/K reads done before P overlays X+Q

  // ---- stage 4/5: P -> LDS (8x 8B stores), O = P @ V ----
  // P is strictly intra-wave (same (mg,h) writes and reads its slice), so no
  // barrier between stores and loads: in-order DS pipe suffices.
  #pragma unroll
  for (int qt = 0; qt < 2; qt++)
    #pragma unroll
    for (int kt = 0; kt < 4; kt++) {
      int row = 32 * mg + 16 * qt + ln16;
      int col = h * 64 + 16 * kt + 4 * lq;
      unsigned int w0 = (unsigned int)f2bf(ST[kt][qt][0]) | ((unsigned int)f2bf(ST[kt][qt][1]) << 16);
      unsigned int w1 = (unsigned int)f2bf(ST[kt][qt][2]) | ((unsigned int)f2bf(ST[kt][qt][3]) << 16);
      i32x2 wv = {(int)w0, (int)w1};
      *(i32x2_a*)(lds + P_OFF + sw(row, col, 256)) = wv;
    }
  f32x4 O[2][2];
  O[0][0] = fz; O[0][1] = fz; O[1][0] = fz; O[1][1] = fz;
  #pragma unroll
  for (int ks = 0; ks < 2; ks++) {
    bf16x8 pf[2], vf[2];
    #pragma unroll
    for (int mt = 0; mt < 2; mt++)
      pf[mt] = *(const bf16x8_a*)(lds + P_OFF + sw(32 * mg + 16 * mt + ln16, h * 64 + 32 * ks + q8, 256));
    #pragma unroll
    for (int nt = 0; nt < 2; nt++)
      vf[nt] = *(const bf16x8_a*)(lds + VT_OFF + sw(h * 32 + 16 * nt + ln16, 32 * ks + q8, 64));
    #pragma unroll
    for (int mt = 0; mt < 2; mt++)
      #pragma unroll
      for (int nt = 0; nt < 2; nt++)
        O[mt][nt] = __builtin_amdgcn_mfma_f32_16x16x32_bf16(pf[mt], vf[nt], O[mt][nt], 0, 0, 0);
  }
  // AO region (old K) is disjoint from P and VT -> store immediately, no barrier
  #pragma unroll
  for (int mt = 0; mt < 2; mt++)
    #pragma unroll
    for (int nt = 0; nt < 2; nt++)
      #pragma unroll
      for (int r = 0; r < 4; r++) {
        int row = 32 * mg + 16 * mt + 4 * lq + r;
        lds[AO_OFF + sw(row, h * 32 + 16 * nt + ln16, 128)] = f2bf(O[mt][nt][r]);
      }
  __syncthreads();  // B3': AO visible (cross-wave)

  // ---- stage 6: out = AO @ proj_w + proj_b (bias folded into C init) ----
  float pb0 = pbf[32 * sub + ln16];
  float pb1 = pbf[32 * sub + 16 + ln16];
  f32x4 acc3[2][2];
  {
    f32x4 c0 = {pb0, pb0, pb0, pb0};
    f32x4 c1 = {pb1, pb1, pb1, pb1};
    acc3[0][0] = c0; acc3[0][1] = c1; acc3[1][0] = c0; acc3[1][1] = c1;
  }
  #pragma unroll
  for (int ks = 0; ks < 4; ks++) {
    bf16x8 a0 = *(const bf16x8_a*)(lds + AO_OFF + sw(32 * mg + ln16, 32 * ks + q8, 128));
    bf16x8 a1 = *(const bf16x8_a*)(lds + AO_OFF + sw(32 * mg + 16 + ln16, 32 * ks + q8, 128));
    bf16x8 b0 = *(const bf16x8_a*)(pwF + (((sub * 2 + 0) * 4 + ks) << 9) + lane * 8);
    bf16x8 b1 = *(const bf16x8_a*)(pwF + (((sub * 2 + 1) * 4 + ks) << 9) + lane * 8);
    acc3[0][0] = __builtin_amdgcn_mfma_f32_16x16x32_bf16(a0, b0, acc3[0][0], 0, 0, 0);
    acc3[0][1] = __builtin_amdgcn_mfma_f32_16x16x32_bf16(a0, b1, acc3[0][1], 0, 0, 0);
    acc3[1][0] = __builtin_amdgcn_mfma_f32_16x16x32_bf16(a1, b0, acc3[1][0], 0, 0, 0);
    acc3[1][1] = __builtin_amdgcn_mfma_f32_16x16x32_bf16(a1, b1, acc3[1][1], 0, 0, 0);
  }
  if (isbf) {
    u16* ob = (u16*)out;
    #pragma unroll
    for (int mt = 0; mt < 2; mt++)
      #pragma unroll
      for (int r = 0; r < 4; r++) {
        int row = 32 * mg + 16 * mt + 4 * lq + r;
        int o = xbase + (row >> 3) * 16384 + (row & 7) * 128 + 32 * sub;
        ob[o + ln16] = f2bf(acc3[mt][0][r]);
        ob[o + 16 + ln16] = f2bf(acc3[mt][1][r]);
      }
  } else {
    float* of = (float*)out;
    #pragma unroll
    for (int mt = 0; mt < 2; mt++)
      #pragma unroll
      for (int r = 0; r < 4; r++) {
        int row = 32 * mg + 16 * mt + 4 * lq + r;
        int o = xbase + (row >> 3) * 16384 + (row & 7) * 128 + 32 * sub;
        of[o + ln16] = acc3[mt][0][r];
        of[o + 16 + ln16] = acc3[mt][1][r];
      }
  }
}

extern "C" void kernel_launch(void* const* d_in, const int* in_sizes, int n_in,
                              void* d_out, int out_size, void* d_ws, size_t ws_size,
                              hipStream_t stream) {
  const void* x      = d_in[0];
  const void* mask   = d_in[1];
  const void* qkv_w  = d_in[2];
  const void* q_bias = d_in[3];
  const void* v_bias = d_in[4];
  const void* ls     = d_in[5];
  const void* cpb_w1 = d_in[6];
  const void* cpb_b1 = d_in[7];
  const void* cpb_w2 = d_in[8];
  const void* proj_w = d_in[9];
  const void* proj_b = d_in[10];
  const int B = in_sizes[0] / (128 * 128 * 128);

  char* ws = (char*)d_ws;
  swin_detect<<<1, 64, 0, stream>>>((const unsigned int*)x,
                                    (unsigned int*)(ws + FLAG_OFF));
  swin_setup<<<258, 256, 0, stream>>>(qkv_w, q_bias, v_bias, ls, cpb_w1, cpb_b1,
                                      cpb_w2, proj_w, proj_b, ws);
  if (ws_size >= MASKF_NEED) {
    swin_setup_mask<<<256, 256, 0, stream>>>(mask, ws);
    swin_main<1><<<B * 256, 512, 0, stream>>>(x, mask, ws, d_out);
  } else {
    swin_main<0><<<B * 256, 512, 0, stream>>>(x, mask, ws, d_out);
  }
}